// Round 7
// baseline (976.293 us; speedup 1.0000x reference)
//
#include <hip/hip_runtime.h>
#include <stdint.h>
#include <stddef.h>

typedef float f32x4 __attribute__((ext_vector_type(4)));
typedef __bf16 bf16x8 __attribute__((ext_vector_type(8)));
typedef short s16x4 __attribute__((ext_vector_type(4)));

#define DEVI static __device__ __forceinline__

DEVI float bf2f(unsigned short u) {
  unsigned int x = ((unsigned int)u) << 16;
  float f;
  __builtin_memcpy(&f, &x, 4);
  return f;
}
DEVI unsigned short f2bf(float f) {
  unsigned int x;
  __builtin_memcpy(&x, &f, 4);
  unsigned int r = (x + 0x7fffu + ((x >> 16) & 1u)) >> 16;
  return (unsigned short)r;
}

DEVI void async16(const void* g, void* l) {
  __builtin_amdgcn_global_load_lds((__attribute__((address_space(1))) void*)g,
                                   (__attribute__((address_space(3))) void*)l,
                                   16, 0, 0);
}

// ---------------- fp32 -> bf16 conversion ----------------
__global__ __launch_bounds__(256) void cvt_bf16(const float* __restrict__ in,
                                                unsigned short* __restrict__ out, int n) {
  int i = (blockIdx.x * 256 + threadIdx.x) * 4;
  if (i >= n) return;
  float4 v = *(const float4*)(in + i);
  s16x4 o;
  o[0] = (short)f2bf(v.x);
  o[1] = (short)f2bf(v.y);
  o[2] = (short)f2bf(v.z);
  o[3] = (short)f2bf(v.w);
  *(s16x4*)(out + i) = o;
}

// ---------------- RoPE table: tab[t][0..63]=cos, tab[t][64..127]=sin ----------------
__global__ __launch_bounds__(256) void rope_table(float* __restrict__ tab) {
  int idx = blockIdx.x * 256 + threadIdx.x;
  if (idx >= 2048 * 64) return;
  int tt = idx >> 6, j = idx & 63;
  float inv = powf(10000.0f, -(float)j * (1.0f / 64.0f));
  float ang = (float)tt * inv;
  tab[tt * 128 + j] = cosf(ang);
  tab[tt * 128 + 64 + j] = sinf(ang);
}

// ---------------- apply RoPE in place; Q additionally pre-scaled by 1/sqrt(hd)*log2(e) ----
__global__ __launch_bounds__(256) void rope_apply(unsigned short* __restrict__ Qg,
                                                  unsigned short* __restrict__ Kg,
                                                  const float* __restrict__ tab) {
  const float S2 = 0.0883883476483184f * 1.44269504088896341f;
  int idx = blockIdx.x * 256 + threadIdx.x;  // bh*2048*64 + t*64 + j
  int j = idx & 63;
  int tt = (idx >> 6) & 2047;
  int bh = idx >> 17;
  size_t base = ((size_t)bh * 2048 + tt) * 128;
  float c = tab[tt * 128 + j], s = tab[tt * 128 + 64 + j];
  float q1 = bf2f(Qg[base + j]), q2 = bf2f(Qg[base + j + 64]);
  Qg[base + j] = f2bf((q1 * c - q2 * s) * S2);
  Qg[base + j + 64] = f2bf((q1 * s + q2 * c) * S2);
  float k1 = bf2f(Kg[base + j]), k2 = bf2f(Kg[base + j + 64]);
  Kg[base + j] = f2bf(k1 * c - k2 * s);
  Kg[base + j + 64] = f2bf(k1 * s + k2 * c);
}

// ---------------- GEMM: C[m][n] = sum_k A[m][k]*B[n][k]  (both row-major, K contiguous)
template <int EPI>
__global__ __launch_bounds__(256) void gemm_bt(const unsigned short* __restrict__ A,
                                               const unsigned short* __restrict__ B,
                                               float* __restrict__ C, int M, int N, int K,
                                               unsigned short* __restrict__ Q,
                                               unsigned short* __restrict__ Kk,
                                               unsigned short* __restrict__ VT) {
  __shared__ __attribute__((aligned(128))) unsigned short As[128 * 64];
  __shared__ __attribute__((aligned(128))) unsigned short Bs[128 * 64];
  const int t = threadIdx.x;
  const int lane = t & 63;
  const int w = t >> 6, wr = w >> 1, wc = w & 1;
  const int g = lane >> 4, lr = lane & 15;
  const int bm = blockIdx.y * 128, bn = blockIdx.x * 128;

  f32x4 acc[4][4] = {};

  const int srow = t >> 3;                 // 0..31: row within a 4KB staging chunk
  const int sslot = (t & 7) ^ (srow & 7);  // inverse-swizzled source 16B slot
  const unsigned short* aptr = A + (size_t)bm * K;
  const unsigned short* bptr = B + (size_t)bn * K;

  for (int k0 = 0; k0 < K; k0 += 64) {
    __syncthreads();
#pragma unroll
    for (int c = 0; c < 4; ++c) {
      int row = c * 32 + srow;
      async16(aptr + (size_t)row * K + k0 + sslot * 8, As + c * 2048 + t * 8);
      async16(bptr + (size_t)row * K + k0 + sslot * 8, Bs + c * 2048 + t * 8);
    }
    __syncthreads();
#pragma unroll
    for (int kk = 0; kk < 2; ++kk) {
      bf16x8 af[4], bfr[4];
#pragma unroll
      for (int i = 0; i < 4; ++i) {
        int row = wr * 64 + i * 16 + lr;
        af[i] = *(const bf16x8*)(As + row * 64 + (((kk * 4 + g) ^ (row & 7)) * 8));
        int rowb = wc * 64 + i * 16 + lr;
        bfr[i] = *(const bf16x8*)(Bs + rowb * 64 + (((kk * 4 + g) ^ (rowb & 7)) * 8));
      }
#pragma unroll
      for (int i = 0; i < 4; ++i)
#pragma unroll
        for (int j = 0; j < 4; ++j)
          acc[i][j] = __builtin_amdgcn_mfma_f32_16x16x32_bf16(af[i], bfr[j], acc[i][j], 0, 0, 0);
    }
  }

  if (EPI == 0) {
#pragma unroll
    for (int i = 0; i < 4; ++i) {
      int m0 = bm + wr * 64 + i * 16 + g * 4;
#pragma unroll
      for (int j = 0; j < 4; ++j) {
        int n = bn + wc * 64 + j * 16 + lr;
#pragma unroll
        for (int r = 0; r < 4; ++r) C[(size_t)(m0 + r) * N + n] = acc[i][j][r];
      }
    }
  } else {
    const int bi = bm >> 11;      // batch index (tile never crosses batch: 2048%128==0)
    const int tbase = bm & 2047;  // t within batch
#pragma unroll
    for (int j = 0; j < 4; ++j) {
      int e = bn + wc * 64 + j * 16 + lr;  // 0..6143 (region uniform per block)
      int region = e >> 11;
      int e2 = e & 2047;
      int h = e2 >> 7, d = e2 & 127;
      int bh = bi * 16 + h;
#pragma unroll
      for (int i = 0; i < 4; ++i) {
        int trow = tbase + wr * 64 + i * 16 + g * 4;
        if (region == 2) {
          s16x4 pk;
#pragma unroll
          for (int r = 0; r < 4; ++r) pk[r] = (short)f2bf(acc[i][j][r]);
          *(s16x4*)(VT + ((size_t)bh * 128 + d) * 2048 + trow) = pk;
        } else {
          unsigned short* dst = (region == 0) ? Q : Kk;
#pragma unroll
          for (int r = 0; r < 4; ++r)
            dst[((size_t)bh * 2048 + trow + r) * 128 + d] = f2bf(acc[i][j][r]);
        }
      }
    }
  }
}

// ---------------- flash attention ----------------
// R7: ZERO-STAGING, BARRIER-FREE. K/V tiles are L1/L2-resident (R5/R6: FETCH
// 49MB total thanks to XCD-affinity swizzle), so LDS staging + double-buffer
// barriers were pure overhead (Common-mistake #7). Each lane reads its 16B
// MFMA fragment straight from global (4 g-lanes form a 64B line). LDS holds
// only the per-wave P bounce (9.2KB). No __syncthreads anywhere: 4 waves run
// fully independently -> TLP covers L2 latency.
// Row-sum via MFMA: l accumulated by 2 extra MFMAs against a ones B-fragment
// (accl), replacing the 16-swizzle shuffle-reduce per tile.
// grid 2048, XCD swizzle: xcd=id&7, bh=xcd*8+(j5>>5), qbi=31-(j5&31) (LPT).
__global__ __launch_bounds__(256) void flash_attn(const unsigned short* __restrict__ Qg,
                                                  const unsigned short* __restrict__ Kg,
                                                  const unsigned short* __restrict__ VTg,
                                                  unsigned short* __restrict__ Yg,
                                                  const int* __restrict__ iscausal,
                                                  const unsigned char* __restrict__ amask) {
  __shared__ __attribute__((aligned(128))) unsigned short Ps[4][16 * 72];

  const int t = threadIdx.x, lane = t & 63, w = t >> 6;
  const int g = lane >> 4, lr = lane & 15;
  const int id = blockIdx.x;
  const int xcd = id & 7, j5 = id >> 3;
  const int bh = xcd * 8 + (j5 >> 5);
  const int qbi = 31 - (j5 & 31);
  const int b = bh >> 4;
  const int qb = qbi * 64;
  const int causal = iscausal[0] != 0;
  const int nt = causal ? (qbi + 1) : 32;

  const unsigned short* qrow = Qg + ((size_t)bh * 2048 + qb + w * 16 + lr) * 128;
  bf16x8 qf[4];
#pragma unroll
  for (int ds = 0; ds < 4; ++ds) qf[ds] = *(const bf16x8*)(qrow + ds * 32 + g * 8);

  const unsigned short* Kbase = Kg + (size_t)bh * 2048 * 128;
  const unsigned short* Vbase = VTg + (size_t)bh * 128 * 2048;

  // constant ones B-fragment for the row-sum MFMA
  unsigned int oi[4] = {0x3F803F80u, 0x3F803F80u, 0x3F803F80u, 0x3F803F80u};
  bf16x8 ones;
  __builtin_memcpy(&ones, oi, 16);

  f32x4 acc[8] = {};
  f32x4 accl = {0.f, 0.f, 0.f, 0.f};  // running row-sum (all cols identical)
  float mrow[4] = {-1e30f, -1e30f, -1e30f, -1e30f};

  for (int kt = 0; kt < nt; ++kt) {
    const int kv0 = kt * 64;

    // ---- QK^T: K fragments straight from global (L1/L2-hit) ----
    f32x4 s[4] = {};
    const unsigned short* Kt = Kbase + (size_t)kv0 * 128 + g * 8;
#pragma unroll
    for (int cf = 0; cf < 4; ++cf) {
      const unsigned short* krow = Kt + (cf * 16 + lr) * 128;
#pragma unroll
      for (int ds = 0; ds < 4; ++ds) {
        bf16x8 kf = *(const bf16x8*)(krow + ds * 32);
        s[cf] = __builtin_amdgcn_mfma_f32_16x16x32_bf16(qf[ds], kf, s[cf], 0, 0, 0);
      }
    }

    const int q0 = qb + w * 16 + g * 4;
    if (causal) {
      if (kt == qbi) {
#pragma unroll
        for (int cf = 0; cf < 4; ++cf) {
          int kvg = kv0 + cf * 16 + lr;
#pragma unroll
          for (int r = 0; r < 4; ++r)
            if (kvg > q0 + r) s[cf][r] = -1e30f;
        }
      }
    } else {
#pragma unroll
      for (int cf = 0; cf < 4; ++cf) {
        int kvg = kv0 + cf * 16 + lr;
        if (!amask[(size_t)b * 2048 + kvg]) {
#pragma unroll
          for (int r = 0; r < 4; ++r) s[cf][r] = -1e30f;
        }
      }
    }

    // ---- row max (16-lane shuffle reduce) ----
    f32x4 mx;
#pragma unroll
    for (int r = 0; r < 4; ++r)
      mx[r] = fmaxf(fmaxf(s[0][r], s[1][r]), fmaxf(s[2][r], s[3][r]));
#pragma unroll
    for (int off = 8; off >= 1; off >>= 1)
#pragma unroll
      for (int r = 0; r < 4; ++r) mx[r] = fmaxf(mx[r], __shfl_xor(mx[r], off));

    // defer-max: only rescale when tile max exceeds running max + 8 (log2 domain)
    bool ok = true;
#pragma unroll
    for (int r = 0; r < 4; ++r) ok = ok && (mx[r] <= mrow[r] + 8.0f);
    if (!__all(ok)) {
#pragma unroll
      for (int r = 0; r < 4; ++r) {
        float mn = fmaxf(mrow[r], mx[r]);
        float corr = exp2f(mrow[r] - mn);
        mrow[r] = mn;
        accl[r] *= corr;
#pragma unroll
        for (int jf = 0; jf < 8; ++jf) acc[jf][r] *= corr;
      }
    }

    // ---- P = exp2(S - m) ----
#pragma unroll
    for (int cf = 0; cf < 4; ++cf)
#pragma unroll
      for (int r = 0; r < 4; ++r) s[cf][r] = exp2f(s[cf][r] - mrow[r]);

    // ---- P bounce through wave-private LDS (transpose to A-fragment) ----
    unsigned short* Pw = &Ps[w][0];
#pragma unroll
    for (int cf = 0; cf < 4; ++cf)
#pragma unroll
      for (int r = 0; r < 4; ++r) Pw[(g * 4 + r) * 72 + cf * 16 + lr] = f2bf(s[cf][r]);
    asm volatile("s_waitcnt lgkmcnt(0)" ::: "memory");
    __builtin_amdgcn_sched_barrier(0);

    bf16x8 pa0 = *(const bf16x8*)(Pw + lr * 72 + g * 8);
    bf16x8 pa1 = *(const bf16x8*)(Pw + lr * 72 + 32 + g * 8);

    // ---- row-sum via MFMA (l += sum_k P): MFMA pipe is idle, VALU isn't ----
    accl = __builtin_amdgcn_mfma_f32_16x16x32_bf16(pa0, ones, accl, 0, 0, 0);
    accl = __builtin_amdgcn_mfma_f32_16x16x32_bf16(pa1, ones, accl, 0, 0, 0);

    // ---- PV: V fragments straight from global ([d][t] layout, 16B contig) ----
#pragma unroll
    for (int jf = 0; jf < 8; ++jf) {
      const unsigned short* vrow = Vbase + (size_t)(jf * 16 + lr) * 2048 + kv0 + g * 8;
      bf16x8 v0 = *(const bf16x8*)(vrow);
      bf16x8 v1 = *(const bf16x8*)(vrow + 32);
      acc[jf] = __builtin_amdgcn_mfma_f32_16x16x32_bf16(pa0, v0, acc[jf], 0, 0, 0);
      acc[jf] = __builtin_amdgcn_mfma_f32_16x16x32_bf16(pa1, v1, acc[jf], 0, 0, 0);
    }
  }

  const int h = bh & 15;
  float rl[4];
#pragma unroll
  for (int r = 0; r < 4; ++r) rl[r] = __builtin_amdgcn_rcpf(accl[r]);
#pragma unroll
  for (int jf = 0; jf < 8; ++jf)
#pragma unroll
    for (int r = 0; r < 4; ++r) {
      int tt = qb + w * 16 + g * 4 + r;
      Yg[((size_t)b * 2048 + tt) * 2048 + h * 128 + jf * 16 + lr] = f2bf(acc[jf][r] * rl[r]);
    }
}

// ---------------- launch ----------------
extern "C" void kernel_launch(void* const* d_in, const int* in_sizes, int n_in, void* d_out,
                              int out_size, void* d_ws, size_t ws_size, hipStream_t stream) {
  const float* x = (const float*)d_in[0];
  const unsigned char* amask = (const unsigned char*)d_in[1];
  const int* iscausal = (const int*)d_in[2];
  const float* wqkv = (const float*)d_in[3];
  const float* wout = (const float*)d_in[4];
  float* out = (float*)d_out;

  const size_t MT = 8192, D = 2048, ND = 6144;
  unsigned short* xb = (unsigned short*)d_ws;
  unsigned short* wqkvb = xb + MT * D;
  unsigned short* woutb = wqkvb + ND * D;
  unsigned short* q = woutb + D * D;
  unsigned short* k = q + MT * D;
  unsigned short* vt = k + MT * D;
  unsigned short* y = vt + MT * D;
  float* tab = (float*)(y + MT * D);
  if (ws_size < (size_t)(100663296) * 2 + 2048 * 128 * 4) return;

  cvt_bf16<<<dim3(16384), dim3(256), 0, stream>>>(x, xb, (int)(MT * D));
  cvt_bf16<<<dim3(12288), dim3(256), 0, stream>>>(wqkv, wqkvb, (int)(ND * D));
  cvt_bf16<<<dim3(4096), dim3(256), 0, stream>>>(wout, woutb, (int)(D * D));
  rope_table<<<dim3(512), dim3(256), 0, stream>>>(tab);
  gemm_bt<1><<<dim3(48, 64), dim3(256), 0, stream>>>(xb, wqkvb, nullptr, 8192, 6144, 2048, q, k, vt);
  rope_apply<<<dim3(32768), dim3(256), 0, stream>>>(q, k, tab);
  flash_attn<<<dim3(2048), dim3(256), 0, stream>>>(q, k, vt, y, iscausal, amask);
  gemm_bt<0><<<dim3(16, 64), dim3(256), 0, stream>>>(y, woutb, out, 8192, 2048, 2048, nullptr,
                                                     nullptr, nullptr);
}

// Round 8
// 578.366 us; speedup vs baseline: 1.6880x; 1.6880x over previous
//
#include <hip/hip_runtime.h>
#include <stdint.h>
#include <stddef.h>

typedef float f32x4 __attribute__((ext_vector_type(4)));
typedef __bf16 bf16x8 __attribute__((ext_vector_type(8)));
typedef short s16x4 __attribute__((ext_vector_type(4)));

#define DEVI static __device__ __forceinline__

DEVI float bf2f(unsigned short u) {
  unsigned int x = ((unsigned int)u) << 16;
  float f;
  __builtin_memcpy(&f, &x, 4);
  return f;
}
DEVI unsigned short f2bf(float f) {
  unsigned int x;
  __builtin_memcpy(&x, &f, 4);
  unsigned int r = (x + 0x7fffu + ((x >> 16) & 1u)) >> 16;
  return (unsigned short)r;
}

DEVI void async16(const void* g, void* l) {
  __builtin_amdgcn_global_load_lds((__attribute__((address_space(1))) void*)g,
                                   (__attribute__((address_space(3))) void*)l,
                                   16, 0, 0);
}

// raw barrier with own-LDS-ops drain; vmcnt NOT touched.
#define BAR_LGKM()                                          \
  do {                                                      \
    asm volatile("s_waitcnt lgkmcnt(0)" ::: "memory");      \
    __builtin_amdgcn_s_barrier();                           \
    __builtin_amdgcn_sched_barrier(0);                      \
  } while (0)

// counted-vmcnt barrier: N loads may stay in flight (T4).
#define BAR_VM(N)                                               \
  do {                                                          \
    asm volatile("s_waitcnt vmcnt(" #N ")" ::: "memory");       \
    __builtin_amdgcn_s_barrier();                               \
    __builtin_amdgcn_sched_barrier(0);                          \
  } while (0)

// ---------------- fp32 -> bf16 conversion ----------------
__global__ __launch_bounds__(256) void cvt_bf16(const float* __restrict__ in,
                                                unsigned short* __restrict__ out, int n) {
  int i = (blockIdx.x * 256 + threadIdx.x) * 4;
  if (i >= n) return;
  float4 v = *(const float4*)(in + i);
  s16x4 o;
  o[0] = (short)f2bf(v.x);
  o[1] = (short)f2bf(v.y);
  o[2] = (short)f2bf(v.z);
  o[3] = (short)f2bf(v.w);
  *(s16x4*)(out + i) = o;
}

// ---------------- RoPE table: tab[t][0..63]=cos, tab[t][64..127]=sin ----------------
__global__ __launch_bounds__(256) void rope_table(float* __restrict__ tab) {
  int idx = blockIdx.x * 256 + threadIdx.x;
  if (idx >= 2048 * 64) return;
  int tt = idx >> 6, j = idx & 63;
  float inv = powf(10000.0f, -(float)j * (1.0f / 64.0f));
  float ang = (float)tt * inv;
  tab[tt * 128 + j] = cosf(ang);
  tab[tt * 128 + 64 + j] = sinf(ang);
}

// ---------------- apply RoPE in place; Q additionally pre-scaled by 1/sqrt(hd)*log2(e) ----
__global__ __launch_bounds__(256) void rope_apply(unsigned short* __restrict__ Qg,
                                                  unsigned short* __restrict__ Kg,
                                                  const float* __restrict__ tab) {
  const float S2 = 0.0883883476483184f * 1.44269504088896341f;
  int idx = blockIdx.x * 256 + threadIdx.x;  // bh*2048*64 + t*64 + j
  int j = idx & 63;
  int tt = (idx >> 6) & 2047;
  int bh = idx >> 17;
  size_t base = ((size_t)bh * 2048 + tt) * 128;
  float c = tab[tt * 128 + j], s = tab[tt * 128 + 64 + j];
  float q1 = bf2f(Qg[base + j]), q2 = bf2f(Qg[base + j + 64]);
  Qg[base + j] = f2bf((q1 * c - q2 * s) * S2);
  Qg[base + j + 64] = f2bf((q1 * s + q2 * c) * S2);
  float k1 = bf2f(Kg[base + j]), k2 = bf2f(Kg[base + j + 64]);
  Kg[base + j] = f2bf(k1 * c - k2 * s);
  Kg[base + j + 64] = f2bf(k1 * s + k2 * c);
}

// ---------------- GEMM: C[m][n] = sum_k A[m][k]*B[n][k]  (both row-major, K contiguous)
// R8: chunked XCD swizzle on flattened block id (nwg%8==0 for both call sites):
// each XCD gets a contiguous run of tiles -> A-panel L2 reuse within an XCD.
template <int EPI>
__global__ __launch_bounds__(256) void gemm_bt(const unsigned short* __restrict__ A,
                                               const unsigned short* __restrict__ B,
                                               float* __restrict__ C, int M, int N, int K,
                                               unsigned short* __restrict__ Q,
                                               unsigned short* __restrict__ Kk,
                                               unsigned short* __restrict__ VT) {
  __shared__ __attribute__((aligned(128))) unsigned short As[128 * 64];
  __shared__ __attribute__((aligned(128))) unsigned short Bs[128 * 64];
  const int t = threadIdx.x;
  const int lane = t & 63;
  const int w = t >> 6, wr = w >> 1, wc = w & 1;
  const int g = lane >> 4, lr = lane & 15;
  const int id = blockIdx.y * gridDim.x + blockIdx.x;
  const int nwg = gridDim.x * gridDim.y;
  const int wg = (id & 7) * (nwg >> 3) + (id >> 3);  // XCD-chunked (nwg%8==0)
  const int bm = (wg / gridDim.x) * 128, bn = (wg % gridDim.x) * 128;

  f32x4 acc[4][4] = {};

  const int srow = t >> 3;                 // 0..31: row within a 4KB staging chunk
  const int sslot = (t & 7) ^ (srow & 7);  // inverse-swizzled source 16B slot
  const unsigned short* aptr = A + (size_t)bm * K;
  const unsigned short* bptr = B + (size_t)bn * K;

  for (int k0 = 0; k0 < K; k0 += 64) {
    __syncthreads();
#pragma unroll
    for (int c = 0; c < 4; ++c) {
      int row = c * 32 + srow;
      async16(aptr + (size_t)row * K + k0 + sslot * 8, As + c * 2048 + t * 8);
      async16(bptr + (size_t)row * K + k0 + sslot * 8, Bs + c * 2048 + t * 8);
    }
    __syncthreads();
#pragma unroll
    for (int kk = 0; kk < 2; ++kk) {
      bf16x8 af[4], bfr[4];
#pragma unroll
      for (int i = 0; i < 4; ++i) {
        int row = wr * 64 + i * 16 + lr;
        af[i] = *(const bf16x8*)(As + row * 64 + (((kk * 4 + g) ^ (row & 7)) * 8));
        int rowb = wc * 64 + i * 16 + lr;
        bfr[i] = *(const bf16x8*)(Bs + rowb * 64 + (((kk * 4 + g) ^ (rowb & 7)) * 8));
      }
#pragma unroll
      for (int i = 0; i < 4; ++i)
#pragma unroll
        for (int j = 0; j < 4; ++j)
          acc[i][j] = __builtin_amdgcn_mfma_f32_16x16x32_bf16(af[i], bfr[j], acc[i][j], 0, 0, 0);
    }
  }

  if (EPI == 0) {
#pragma unroll
    for (int i = 0; i < 4; ++i) {
      int m0 = bm + wr * 64 + i * 16 + g * 4;
#pragma unroll
      for (int j = 0; j < 4; ++j) {
        int n = bn + wc * 64 + j * 16 + lr;
#pragma unroll
        for (int r = 0; r < 4; ++r) C[(size_t)(m0 + r) * N + n] = acc[i][j][r];
      }
    }
  } else {
    const int bi = bm >> 11;      // batch index (tile never crosses batch: 2048%128==0)
    const int tbase = bm & 2047;  // t within batch
#pragma unroll
    for (int j = 0; j < 4; ++j) {
      int e = bn + wc * 64 + j * 16 + lr;  // 0..6143 (region uniform per block)
      int region = e >> 11;
      int e2 = e & 2047;
      int h = e2 >> 7, d = e2 & 127;
      int bh = bi * 16 + h;
#pragma unroll
      for (int i = 0; i < 4; ++i) {
        int trow = tbase + wr * 64 + i * 16 + g * 4;
        if (region == 2) {
          s16x4 pk;
#pragma unroll
          for (int r = 0; r < 4; ++r) pk[r] = (short)f2bf(acc[i][j][r]);
          *(s16x4*)(VT + ((size_t)bh * 128 + d) * 2048 + trow) = pk;
        } else {
          unsigned short* dst = (region == 0) ? Q : Kk;
#pragma unroll
          for (int r = 0; r < 4; ++r)
            dst[((size_t)bh * 2048 + trow + r) * 128 + d] = f2bf(acc[i][j][r]);
        }
      }
    }
  }
}

// ---------------- flash attention ----------------
// R8 = R6 dbuf global_load_lds pipeline (best measured: 243us) + two softmax cuts:
//  * row-sum via MFMA-ones into accl (R7-verified): kills 16 bpermute + 16 adds/tile
//  * lazy row-max: common case decided by lane-local max + __all (no cross-lane
//    reduce); full 16-lane bpermute reduce + rescale only when bound exceeded.
// grid 2048, XCD-affinity swizzle, LPT. LDS 74.75KB (2 blocks/CU).
__global__ __launch_bounds__(256) void flash_attn(const unsigned short* __restrict__ Qg,
                                                  const unsigned short* __restrict__ Kg,
                                                  const unsigned short* __restrict__ VTg,
                                                  unsigned short* __restrict__ Yg,
                                                  const int* __restrict__ iscausal,
                                                  const unsigned char* __restrict__ amask) {
  __shared__ __attribute__((aligned(128))) unsigned short Ks[2][64 * 128];
  __shared__ __attribute__((aligned(128))) unsigned short Vs[2][128 * 64];
  __shared__ __attribute__((aligned(128))) unsigned short Ps[4][16 * 72];

  const int t = threadIdx.x, lane = t & 63, w = t >> 6;
  const int g = lane >> 4, lr = lane & 15;
  const int id = blockIdx.x;
  const int xcd = id & 7, j5 = id >> 3;
  const int bh = xcd * 8 + (j5 >> 5);
  const int qbi = 31 - (j5 & 31);
  const int b = bh >> 4;
  const int qb = qbi * 64;
  const int causal = iscausal[0] != 0;
  const int nt = causal ? (qbi + 1) : 32;

  const unsigned short* qrow = Qg + ((size_t)bh * 2048 + qb + w * 16 + lr) * 128;
  bf16x8 qf[4];
#pragma unroll
  for (int ds = 0; ds < 4; ++ds) qf[ds] = *(const bf16x8*)(qrow + ds * 32 + g * 8);

  const unsigned short* Kbase = Kg + (size_t)bh * 2048 * 128;
  const unsigned short* Vbase = VTg + (size_t)bh * 128 * 2048;

  const int rK = t >> 4, sK = ((t & 15) ^ rK);  // source slot, XOR-swizzled
  const int rV = t >> 3, sV = ((t & 7) ^ ((t >> 3) & 7));

#define STAGE(KT, P)                                                                    \
  do {                                                                                  \
    const int _kv = (KT) * 64;                                                          \
    _Pragma("unroll") for (int c = 0; c < 4; ++c)                                       \
        async16(Kbase + (size_t)(_kv + c * 16 + rK) * 128 + sK * 8,                     \
                &Ks[P][c * 2048 + t * 8]);                                              \
    _Pragma("unroll") for (int c = 0; c < 4; ++c)                                       \
        async16(Vbase + (size_t)(c * 32 + rV) * 2048 + _kv + sV * 8,                    \
                &Vs[P][c * 2048 + t * 8]);                                              \
  } while (0)

  // constant ones B-fragment for the row-sum MFMA
  unsigned int oi[4] = {0x3F803F80u, 0x3F803F80u, 0x3F803F80u, 0x3F803F80u};
  bf16x8 ones;
  __builtin_memcpy(&ones, oi, 16);

  f32x4 acc[8] = {};
  f32x4 accl = {0.f, 0.f, 0.f, 0.f};  // running row-sum via MFMA-ones
  float mrow[4] = {-1e30f, -1e30f, -1e30f, -1e30f};

  STAGE(0, 0);  // prologue: 8 loads in flight

  for (int kt = 0; kt < nt; ++kt) {
    const int p = kt & 1;
    const int kv0 = kt * 64;
    if (kt + 1 < nt) {
      STAGE(kt + 1, p ^ 1);
      BAR_VM(8);
    } else {
      BAR_VM(0);
    }

    f32x4 s[4] = {};
    __builtin_amdgcn_s_setprio(1);
#pragma unroll
    for (int cf = 0; cf < 4; ++cf)
#pragma unroll
      for (int ds = 0; ds < 4; ++ds) {
        bf16x8 kf = *(const bf16x8*)(&Ks[p][(cf * 16 + lr) * 128 + (((ds * 4 + g) ^ lr) * 8)]);
        s[cf] = __builtin_amdgcn_mfma_f32_16x16x32_bf16(qf[ds], kf, s[cf], 0, 0, 0);
      }
    __builtin_amdgcn_s_setprio(0);

    const int q0 = qb + w * 16 + g * 4;
    if (causal) {
      if (kt == qbi) {
#pragma unroll
        for (int cf = 0; cf < 4; ++cf) {
          int kvg = kv0 + cf * 16 + lr;
#pragma unroll
          for (int r = 0; r < 4; ++r)
            if (kvg > q0 + r) s[cf][r] = -1e30f;
        }
      }
    } else {
#pragma unroll
      for (int cf = 0; cf < 4; ++cf) {
        int kvg = kv0 + cf * 16 + lr;
        if (!amask[(size_t)b * 2048 + kvg]) {
#pragma unroll
          for (int r = 0; r < 4; ++r) s[cf][r] = -1e30f;
        }
      }
    }

    // ---- lazy max: lane-local max only in the common case ----
    f32x4 lm;
#pragma unroll
    for (int r = 0; r < 4; ++r)
      lm[r] = fmaxf(fmaxf(s[0][r], s[1][r]), fmaxf(s[2][r], s[3][r]));
    bool ok = true;
#pragma unroll
    for (int r = 0; r < 4; ++r) ok = ok && (lm[r] <= mrow[r] + 8.0f);
    if (!__all(ok)) {
      // full row-max reduce + rescale (rare after first tiles)
      f32x4 mx = lm;
#pragma unroll
      for (int off = 8; off >= 1; off >>= 1)
#pragma unroll
        for (int r = 0; r < 4; ++r) mx[r] = fmaxf(mx[r], __shfl_xor(mx[r], off));
#pragma unroll
      for (int r = 0; r < 4; ++r) {
        float mn = fmaxf(mrow[r], mx[r]);
        float corr = exp2f(mrow[r] - mn);
        mrow[r] = mn;
        accl[r] *= corr;
#pragma unroll
        for (int jf = 0; jf < 8; ++jf) acc[jf][r] *= corr;
      }
    }

    // ---- P = exp2(S - m) ----
#pragma unroll
    for (int cf = 0; cf < 4; ++cf)
#pragma unroll
      for (int r = 0; r < 4; ++r) s[cf][r] = exp2f(s[cf][r] - mrow[r]);

    // ---- P bounce through wave-private padded LDS ----
    unsigned short* Pw = &Ps[w][0];
#pragma unroll
    for (int cf = 0; cf < 4; ++cf)
#pragma unroll
      for (int r = 0; r < 4; ++r) Pw[(g * 4 + r) * 72 + cf * 16 + lr] = f2bf(s[cf][r]);
    asm volatile("s_waitcnt lgkmcnt(0)" ::: "memory");
    __builtin_amdgcn_sched_barrier(0);

    bf16x8 pa0 = *(const bf16x8*)(Pw + lr * 72 + g * 8);
    bf16x8 pa1 = *(const bf16x8*)(Pw + lr * 72 + 32 + g * 8);

    // ---- row-sum via MFMA (accl += sum_k P) ----
    accl = __builtin_amdgcn_mfma_f32_16x16x32_bf16(pa0, ones, accl, 0, 0, 0);
    accl = __builtin_amdgcn_mfma_f32_16x16x32_bf16(pa1, ones, accl, 0, 0, 0);

    __builtin_amdgcn_s_setprio(1);
#pragma unroll
    for (int jf = 0; jf < 8; ++jf) {
      bf16x8 v0 = *(const bf16x8*)(&Vs[p][(jf * 16 + lr) * 64 + ((g ^ (lr & 7)) * 8)]);
      bf16x8 v1 = *(const bf16x8*)(&Vs[p][(jf * 16 + lr) * 64 + (((4 + g) ^ (lr & 7)) * 8)]);
      acc[jf] = __builtin_amdgcn_mfma_f32_16x16x32_bf16(pa0, v0, acc[jf], 0, 0, 0);
      acc[jf] = __builtin_amdgcn_mfma_f32_16x16x32_bf16(pa1, v1, acc[jf], 0, 0, 0);
    }
    __builtin_amdgcn_s_setprio(0);

    // end: all this tile's LDS reads done everywhere -> buf[p] may be restaged
    BAR_LGKM();
  }
#undef STAGE

  const int h = bh & 15;
  float rl[4];
#pragma unroll
  for (int r = 0; r < 4; ++r) rl[r] = __builtin_amdgcn_rcpf(accl[r]);
#pragma unroll
  for (int jf = 0; jf < 8; ++jf)
#pragma unroll
    for (int r = 0; r < 4; ++r) {
      int tt = qb + w * 16 + g * 4 + r;
      Yg[((size_t)b * 2048 + tt) * 2048 + h * 128 + jf * 16 + lr] = f2bf(acc[jf][r] * rl[r]);
    }
}

// ---------------- launch ----------------
extern "C" void kernel_launch(void* const* d_in, const int* in_sizes, int n_in, void* d_out,
                              int out_size, void* d_ws, size_t ws_size, hipStream_t stream) {
  const float* x = (const float*)d_in[0];
  const unsigned char* amask = (const unsigned char*)d_in[1];
  const int* iscausal = (const int*)d_in[2];
  const float* wqkv = (const float*)d_in[3];
  const float* wout = (const float*)d_in[4];
  float* out = (float*)d_out;

  const size_t MT = 8192, D = 2048, ND = 6144;
  unsigned short* xb = (unsigned short*)d_ws;
  unsigned short* wqkvb = xb + MT * D;
  unsigned short* woutb = wqkvb + ND * D;
  unsigned short* q = woutb + D * D;
  unsigned short* k = q + MT * D;
  unsigned short* vt = k + MT * D;
  unsigned short* y = vt + MT * D;
  float* tab = (float*)(y + MT * D);
  if (ws_size < (size_t)(100663296) * 2 + 2048 * 128 * 4) return;

  cvt_bf16<<<dim3(16384), dim3(256), 0, stream>>>(x, xb, (int)(MT * D));
  cvt_bf16<<<dim3(12288), dim3(256), 0, stream>>>(wqkv, wqkvb, (int)(ND * D));
  cvt_bf16<<<dim3(4096), dim3(256), 0, stream>>>(wout, woutb, (int)(D * D));
  rope_table<<<dim3(512), dim3(256), 0, stream>>>(tab);
  gemm_bt<1><<<dim3(48, 64), dim3(256), 0, stream>>>(xb, wqkvb, nullptr, 8192, 6144, 2048, q, k, vt);
  rope_apply<<<dim3(32768), dim3(256), 0, stream>>>(q, k, tab);
  flash_attn<<<dim3(2048), dim3(256), 0, stream>>>(q, k, vt, y, iscausal, amask);
  gemm_bt<0><<<dim3(16, 64), dim3(256), 0, stream>>>(y, woutb, out, 8192, 2048, 2048, nullptr,
                                                     nullptr, nullptr);
}

// Round 9
// 518.939 us; speedup vs baseline: 1.8813x; 1.1145x over previous
//
#include <hip/hip_runtime.h>
#include <stdint.h>
#include <stddef.h>

typedef float f32x4 __attribute__((ext_vector_type(4)));
typedef __bf16 bf16x8 __attribute__((ext_vector_type(8)));
typedef short s16x4 __attribute__((ext_vector_type(4)));

#define DEVI static __device__ __forceinline__

DEVI float bf2f(unsigned short u) {
  unsigned int x = ((unsigned int)u) << 16;
  float f;
  __builtin_memcpy(&f, &x, 4);
  return f;
}
DEVI unsigned short f2bf(float f) {
  unsigned int x;
  __builtin_memcpy(&x, &f, 4);
  unsigned int r = (x + 0x7fffu + ((x >> 16) & 1u)) >> 16;
  return (unsigned short)r;
}

DEVI void async16(const void* g, void* l) {
  __builtin_amdgcn_global_load_lds((__attribute__((address_space(1))) void*)g,
                                   (__attribute__((address_space(3))) void*)l,
                                   16, 0, 0);
}

// raw barrier with own-LDS-ops drain; vmcnt NOT touched.
#define BAR_LGKM()                                          \
  do {                                                      \
    asm volatile("s_waitcnt lgkmcnt(0)" ::: "memory");      \
    __builtin_amdgcn_s_barrier();                           \
    __builtin_amdgcn_sched_barrier(0);                      \
  } while (0)

// counted-vmcnt barrier: N loads may stay in flight (T4).
#define BAR_VM(N)                                               \
  do {                                                          \
    asm volatile("s_waitcnt vmcnt(" #N ")" ::: "memory");       \
    __builtin_amdgcn_s_barrier();                               \
    __builtin_amdgcn_sched_barrier(0);                          \
  } while (0)

// ---------------- fp32 -> bf16 conversion ----------------
__global__ __launch_bounds__(256) void cvt_bf16(const float* __restrict__ in,
                                                unsigned short* __restrict__ out, int n) {
  int i = (blockIdx.x * 256 + threadIdx.x) * 4;
  if (i >= n) return;
  float4 v = *(const float4*)(in + i);
  s16x4 o;
  o[0] = (short)f2bf(v.x);
  o[1] = (short)f2bf(v.y);
  o[2] = (short)f2bf(v.z);
  o[3] = (short)f2bf(v.w);
  *(s16x4*)(out + i) = o;
}

// ---------------- RoPE table: tab[t][0..63]=cos, tab[t][64..127]=sin ----------------
__global__ __launch_bounds__(256) void rope_table(float* __restrict__ tab) {
  int idx = blockIdx.x * 256 + threadIdx.x;
  if (idx >= 2048 * 64) return;
  int tt = idx >> 6, j = idx & 63;
  float inv = powf(10000.0f, -(float)j * (1.0f / 64.0f));
  float ang = (float)tt * inv;
  tab[tt * 128 + j] = cosf(ang);
  tab[tt * 128 + 64 + j] = sinf(ang);
}

// ---------------- RoPE apply, vectorized x4; Q pre-scaled by 1/sqrt(hd)*log2(e) ----
__global__ __launch_bounds__(256) void rope_apply(unsigned short* __restrict__ Qg,
                                                  unsigned short* __restrict__ Kg,
                                                  const float* __restrict__ tab) {
  const float S2 = 0.0883883476483184f * 1.44269504088896341f;
  int idx = blockIdx.x * 256 + threadIdx.x;  // bh*2048*16 + tt*16 + j4
  int j4 = idx & 15;
  int tt = (idx >> 4) & 2047;
  int bh = idx >> 15;
  size_t base = ((size_t)bh * 2048 + tt) * 128;
  f32x4 c4 = *(const f32x4*)(tab + tt * 128 + j4 * 4);
  f32x4 s4 = *(const f32x4*)(tab + tt * 128 + 64 + j4 * 4);
  s16x4 q1 = *(const s16x4*)(Qg + base + j4 * 4);
  s16x4 q2 = *(const s16x4*)(Qg + base + 64 + j4 * 4);
  s16x4 k1 = *(const s16x4*)(Kg + base + j4 * 4);
  s16x4 k2 = *(const s16x4*)(Kg + base + 64 + j4 * 4);
  s16x4 o1, o2, p1, p2;
#pragma unroll
  for (int r = 0; r < 4; ++r) {
    float c = c4[r], s = s4[r];
    float a = bf2f((unsigned short)q1[r]), b2 = bf2f((unsigned short)q2[r]);
    o1[r] = (short)f2bf((a * c - b2 * s) * S2);
    o2[r] = (short)f2bf((a * s + b2 * c) * S2);
    float ka = bf2f((unsigned short)k1[r]), kb = bf2f((unsigned short)k2[r]);
    p1[r] = (short)f2bf(ka * c - kb * s);
    p2[r] = (short)f2bf(ka * s + kb * c);
  }
  *(s16x4*)(Qg + base + j4 * 4) = o1;
  *(s16x4*)(Qg + base + 64 + j4 * 4) = o2;
  *(s16x4*)(Kg + base + j4 * 4) = p1;
  *(s16x4*)(Kg + base + 64 + j4 * 4) = p2;
}

// ---------------- 256x256 8-phase GEMM: C[m][n] = sum_k A[m][k]*B[n][k] ----------------
// 512 thr = 8 waves (2M x 4N); wave output 128x64 = acc[8][4] f32x4. BK=64,
// 2 K-tiles (128KB LDS) resident; half-tile = K-half (16KB contiguous region,
// 2 global_load_lds/thread). 8 phases/iter over 2 K-tiles: phase = (kh, C-half),
// B-frags reused across the C-half pair. One half-tile staged per phase into the
// slot freed the previous phase; vmcnt(6) only at phases r3/r7 (3 half-tiles =
// 6 loads stay in flight). Per-thread 2-bit XOR unit swizzle -> <=2-way LDS
// conflicts. EPI as before (0: fp32 C; 1: QKV scatter to Q,K,VT).
template <int EPI>
__global__ __launch_bounds__(512) void gemm256(const unsigned short* __restrict__ A,
                                               const unsigned short* __restrict__ B,
                                               float* __restrict__ C, int M, int N, int K,
                                               unsigned short* __restrict__ Q,
                                               unsigned short* __restrict__ Kk,
                                               unsigned short* __restrict__ VT) {
  __shared__ __attribute__((aligned(128))) unsigned short Al[2 * 16384];
  __shared__ __attribute__((aligned(128))) unsigned short Bl[2 * 16384];
  const int t = threadIdx.x;
  const int lane = t & 63;
  const int w = t >> 6, wr = w >> 2, wc = w & 3;
  const int g = lane >> 4, lr = lane & 15;

  const int id = blockIdx.y * gridDim.x + blockIdx.x;
  const int nwg = gridDim.x * gridDim.y;
  const int wg = (id & 7) * (nwg >> 3) + (id >> 3);  // XCD-chunked (nwg%8==0)
  const int bm = (wg / gridDim.x) * 256, bn = (wg % gridDim.x) * 256;

  const unsigned short* aptr = A + (size_t)bm * K;
  const unsigned short* bptr = B + (size_t)bn * K;

  // staging: thread t, load l: row = l*128 + (t>>2), dest unit j = t&3.
  // LDS(region, row, j) holds M[row][kh*32 + (j ^ swz(row))*8], swz = (r&3) ^
  // (((r>>2)&1)<<1) ^ ((r>>3)&1).
  const int col8 = (t & 3) ^ ((t >> 2) & 3) ^ (((t >> 4) & 1) << 1) ^ ((t >> 5) & 1);
  const size_t srcOff0 = (size_t)(t >> 2) * K + col8 * 8;
  const size_t srcL = (size_t)128 * K;

#define STGA(p, kh, kt)                                                               \
  do {                                                                                \
    async16(aptr + srcOff0 + (size_t)(kt) * 64 + (kh) * 32,                           \
            Al + (p) * 16384 + (kh) * 8192 + t * 8);                                  \
    async16(aptr + srcOff0 + srcL + (size_t)(kt) * 64 + (kh) * 32,                    \
            Al + (p) * 16384 + (kh) * 8192 + 4096 + t * 8);                           \
  } while (0)
#define STGB(p, kh, kt)                                                               \
  do {                                                                                \
    async16(bptr + srcOff0 + (size_t)(kt) * 64 + (kh) * 32,                           \
            Bl + (p) * 16384 + (kh) * 8192 + t * 8);                                  \
    async16(bptr + srcOff0 + srcL + (size_t)(kt) * 64 + (kh) * 32,                    \
            Bl + (p) * 16384 + (kh) * 8192 + 4096 + t * 8);                           \
  } while (0)

  // frag reads: unit j = g ^ swz(lr) (row-base multiples of 16 -> swz depends on lr only)
  const int ju = (g ^ (lr & 3) ^ (((lr >> 2) & 1) << 1) ^ ((lr >> 3) & 1)) * 8;
  const int arow = (wr * 128 + lr) * 32 + ju;
  const int brow = (wc * 64 + lr) * 32 + ju;

#define LDA(p, kh, ch)                                                                \
  _Pragma("unroll") for (int mf = 0; mf < 4; ++mf) af[mf] =                           \
      *(const bf16x8*)(Al + (p) * 16384 + (kh) * 8192 + arow + (ch) * 2048 + mf * 512);
#define LDB(p, kh)                                                                    \
  _Pragma("unroll") for (int nf = 0; nf < 4; ++nf) bf[nf] =                           \
      *(const bf16x8*)(Bl + (p) * 16384 + (kh) * 8192 + brow + nf * 512);
#define MMA(ch)                                                                       \
  __builtin_amdgcn_s_setprio(1);                                                      \
  _Pragma("unroll") for (int mf = 0; mf < 4; ++mf)                                    \
      _Pragma("unroll") for (int nf = 0; nf < 4; ++nf) acc[(ch) * 4 + mf][nf] =       \
          __builtin_amdgcn_mfma_f32_16x16x32_bf16(af[mf], bf[nf],                     \
                                                  acc[(ch) * 4 + mf][nf], 0, 0, 0);   \
  __builtin_amdgcn_s_setprio(0);
#define BARR()                            \
  do {                                    \
    __builtin_amdgcn_s_barrier();         \
    __builtin_amdgcn_sched_barrier(0);    \
  } while (0)
#define WLG()                                              \
  do {                                                     \
    asm volatile("s_waitcnt lgkmcnt(0)" ::: "memory");     \
    __builtin_amdgcn_sched_barrier(0);                     \
  } while (0)

  f32x4 acc[8][4] = {};

  // prologue: tile0 fully + tile1 {B.kh0, A.kh0, B.kh1}; A.kh1(1) staged at r0.
  STGA(0, 0, 0);
  STGB(0, 0, 0);
  STGA(0, 1, 0);
  STGB(0, 1, 0);
  STGB(1, 0, 1);
  STGA(1, 0, 1);
  STGB(1, 1, 1);
  asm volatile("s_waitcnt vmcnt(6)" ::: "memory");  // tile0's 4 halves landed
  BARR();

  const int NITER = K >> 7;
  for (int i = 0; i < NITER; ++i) {
    const bool G = (i + 1 < NITER);
    const int t1 = 2 * i + 1, t2 = 2 * i + 2, t3 = 2 * i + 3;
    bf16x8 af[4], bf[4];

    // r0: tile 2i, kh0, ch0 (+B); stage A.kh1(t1)
    LDA(0, 0, 0);
    LDB(0, 0);
    STGA(1, 1, t1);
    BARR();
    WLG();
    MMA(0);
    BARR();
    // r1: kh0, ch1 (reuse B); stage B.kh0(t2)
    LDA(0, 0, 1);
    if (G) STGB(0, 0, t2);
    BARR();
    WLG();
    MMA(1);
    BARR();
    // r2: kh1, ch0 (+B); stage A.kh0(t2)
    LDA(0, 1, 0);
    LDB(0, 1);
    if (G) STGA(0, 0, t2);
    BARR();
    WLG();
    MMA(0);
    BARR();
    // r3: kh1, ch1; stage B.kh1(t2); counted vmcnt
    LDA(0, 1, 1);
    if (G) STGB(0, 1, t2);
    asm volatile("s_waitcnt vmcnt(6)" ::: "memory");
    BARR();
    WLG();
    MMA(1);
    BARR();
    // r4: tile 2i+1, kh0, ch0 (+B); stage A.kh1(t2)
    LDA(1, 0, 0);
    LDB(1, 0);
    if (G) STGA(0, 1, t2);
    BARR();
    WLG();
    MMA(0);
    BARR();
    // r5: kh0, ch1; stage B.kh0(t3)
    LDA(1, 0, 1);
    if (G) STGB(1, 0, t3);
    BARR();
    WLG();
    MMA(1);
    BARR();
    // r6: kh1, ch0 (+B); stage A.kh0(t3)
    LDA(1, 1, 0);
    LDB(1, 1);
    if (G) STGA(1, 0, t3);
    BARR();
    WLG();
    MMA(0);
    BARR();
    // r7: kh1, ch1; stage B.kh1(t3); counted vmcnt
    LDA(1, 1, 1);
    if (G) STGB(1, 1, t3);
    asm volatile("s_waitcnt vmcnt(6)" ::: "memory");
    BARR();
    WLG();
    MMA(1);
    BARR();
  }
#undef STGA
#undef STGB
#undef LDA
#undef LDB
#undef MMA
#undef BARR
#undef WLG

  // epilogue: acc[m'][nf], m' -> row offset (m'>>2)*64 + (m'&3)*16
  if (EPI == 0) {
#pragma unroll
    for (int mp = 0; mp < 8; ++mp) {
      int m0 = bm + wr * 128 + (mp >> 2) * 64 + (mp & 3) * 16 + g * 4;
#pragma unroll
      for (int nf = 0; nf < 4; ++nf) {
        int n = bn + wc * 64 + nf * 16 + lr;
#pragma unroll
        for (int r = 0; r < 4; ++r) C[(size_t)(m0 + r) * N + n] = acc[mp][nf][r];
      }
    }
  } else {
    const int bi = bm >> 11;      // batch (2048%256==0: no tile crosses batch)
    const int tbase = bm & 2047;
#pragma unroll
    for (int nf = 0; nf < 4; ++nf) {
      int e = bn + wc * 64 + nf * 16 + lr;  // region uniform per block
      int region = e >> 11;
      int e2 = e & 2047;
      int h = e2 >> 7, d = e2 & 127;
      int bh = bi * 16 + h;
#pragma unroll
      for (int mp = 0; mp < 8; ++mp) {
        int trow = tbase + wr * 128 + (mp >> 2) * 64 + (mp & 3) * 16 + g * 4;
        if (region == 2) {
          s16x4 pk;
#pragma unroll
          for (int r = 0; r < 4; ++r) pk[r] = (short)f2bf(acc[mp][nf][r]);
          *(s16x4*)(VT + ((size_t)bh * 128 + d) * 2048 + trow) = pk;
        } else {
          unsigned short* dst = (region == 0) ? Q : Kk;
#pragma unroll
          for (int r = 0; r < 4; ++r)
            dst[((size_t)bh * 2048 + trow + r) * 128 + d] = f2bf(acc[mp][nf][r]);
        }
      }
    }
  }
}

// ---------------- flash attention (R8, unchanged) ----------------
__global__ __launch_bounds__(256) void flash_attn(const unsigned short* __restrict__ Qg,
                                                  const unsigned short* __restrict__ Kg,
                                                  const unsigned short* __restrict__ VTg,
                                                  unsigned short* __restrict__ Yg,
                                                  const int* __restrict__ iscausal,
                                                  const unsigned char* __restrict__ amask) {
  __shared__ __attribute__((aligned(128))) unsigned short Ks[2][64 * 128];
  __shared__ __attribute__((aligned(128))) unsigned short Vs[2][128 * 64];
  __shared__ __attribute__((aligned(128))) unsigned short Ps[4][16 * 72];

  const int t = threadIdx.x, lane = t & 63, w = t >> 6;
  const int g = lane >> 4, lr = lane & 15;
  const int id = blockIdx.x;
  const int xcd = id & 7, j5 = id >> 3;
  const int bh = xcd * 8 + (j5 >> 5);
  const int qbi = 31 - (j5 & 31);
  const int b = bh >> 4;
  const int qb = qbi * 64;
  const int causal = iscausal[0] != 0;
  const int nt = causal ? (qbi + 1) : 32;

  const unsigned short* qrow = Qg + ((size_t)bh * 2048 + qb + w * 16 + lr) * 128;
  bf16x8 qf[4];
#pragma unroll
  for (int ds = 0; ds < 4; ++ds) qf[ds] = *(const bf16x8*)(qrow + ds * 32 + g * 8);

  const unsigned short* Kbase = Kg + (size_t)bh * 2048 * 128;
  const unsigned short* Vbase = VTg + (size_t)bh * 128 * 2048;

  const int rK = t >> 4, sK = ((t & 15) ^ rK);
  const int rV = t >> 3, sV = ((t & 7) ^ ((t >> 3) & 7));

#define STAGE(KT, P)                                                                    \
  do {                                                                                  \
    const int _kv = (KT) * 64;                                                          \
    _Pragma("unroll") for (int c = 0; c < 4; ++c)                                       \
        async16(Kbase + (size_t)(_kv + c * 16 + rK) * 128 + sK * 8,                     \
                &Ks[P][c * 2048 + t * 8]);                                              \
    _Pragma("unroll") for (int c = 0; c < 4; ++c)                                       \
        async16(Vbase + (size_t)(c * 32 + rV) * 2048 + _kv + sV * 8,                    \
                &Vs[P][c * 2048 + t * 8]);                                              \
  } while (0)

  unsigned int oi[4] = {0x3F803F80u, 0x3F803F80u, 0x3F803F80u, 0x3F803F80u};
  bf16x8 ones;
  __builtin_memcpy(&ones, oi, 16);

  f32x4 acc[8] = {};
  f32x4 accl = {0.f, 0.f, 0.f, 0.f};
  float mrow[4] = {-1e30f, -1e30f, -1e30f, -1e30f};

  STAGE(0, 0);

  for (int kt = 0; kt < nt; ++kt) {
    const int p = kt & 1;
    const int kv0 = kt * 64;
    if (kt + 1 < nt) {
      STAGE(kt + 1, p ^ 1);
      BAR_VM(8);
    } else {
      BAR_VM(0);
    }

    f32x4 s[4] = {};
    __builtin_amdgcn_s_setprio(1);
#pragma unroll
    for (int cf = 0; cf < 4; ++cf)
#pragma unroll
      for (int ds = 0; ds < 4; ++ds) {
        bf16x8 kf = *(const bf16x8*)(&Ks[p][(cf * 16 + lr) * 128 + (((ds * 4 + g) ^ lr) * 8)]);
        s[cf] = __builtin_amdgcn_mfma_f32_16x16x32_bf16(qf[ds], kf, s[cf], 0, 0, 0);
      }
    __builtin_amdgcn_s_setprio(0);

    const int q0 = qb + w * 16 + g * 4;
    if (causal) {
      if (kt == qbi) {
#pragma unroll
        for (int cf = 0; cf < 4; ++cf) {
          int kvg = kv0 + cf * 16 + lr;
#pragma unroll
          for (int r = 0; r < 4; ++r)
            if (kvg > q0 + r) s[cf][r] = -1e30f;
        }
      }
    } else {
#pragma unroll
      for (int cf = 0; cf < 4; ++cf) {
        int kvg = kv0 + cf * 16 + lr;
        if (!amask[(size_t)b * 2048 + kvg]) {
#pragma unroll
          for (int r = 0; r < 4; ++r) s[cf][r] = -1e30f;
        }
      }
    }

    f32x4 lm;
#pragma unroll
    for (int r = 0; r < 4; ++r)
      lm[r] = fmaxf(fmaxf(s[0][r], s[1][r]), fmaxf(s[2][r], s[3][r]));
    bool ok = true;
#pragma unroll
    for (int r = 0; r < 4; ++r) ok = ok && (lm[r] <= mrow[r] + 8.0f);
    if (!__all(ok)) {
      f32x4 mx = lm;
#pragma unroll
      for (int off = 8; off >= 1; off >>= 1)
#pragma unroll
        for (int r = 0; r < 4; ++r) mx[r] = fmaxf(mx[r], __shfl_xor(mx[r], off));
#pragma unroll
      for (int r = 0; r < 4; ++r) {
        float mn = fmaxf(mrow[r], mx[r]);
        float corr = exp2f(mrow[r] - mn);
        mrow[r] = mn;
        accl[r] *= corr;
#pragma unroll
        for (int jf = 0; jf < 8; ++jf) acc[jf][r] *= corr;
      }
    }

#pragma unroll
    for (int cf = 0; cf < 4; ++cf)
#pragma unroll
      for (int r = 0; r < 4; ++r) s[cf][r] = exp2f(s[cf][r] - mrow[r]);

    unsigned short* Pw = &Ps[w][0];
#pragma unroll
    for (int cf = 0; cf < 4; ++cf)
#pragma unroll
      for (int r = 0; r < 4; ++r) Pw[(g * 4 + r) * 72 + cf * 16 + lr] = f2bf(s[cf][r]);
    asm volatile("s_waitcnt lgkmcnt(0)" ::: "memory");
    __builtin_amdgcn_sched_barrier(0);

    bf16x8 pa0 = *(const bf16x8*)(Pw + lr * 72 + g * 8);
    bf16x8 pa1 = *(const bf16x8*)(Pw + lr * 72 + 32 + g * 8);

    accl = __builtin_amdgcn_mfma_f32_16x16x32_bf16(pa0, ones, accl, 0, 0, 0);
    accl = __builtin_amdgcn_mfma_f32_16x16x32_bf16(pa1, ones, accl, 0, 0, 0);

    __builtin_amdgcn_s_setprio(1);
#pragma unroll
    for (int jf = 0; jf < 8; ++jf) {
      bf16x8 v0 = *(const bf16x8*)(&Vs[p][(jf * 16 + lr) * 64 + ((g ^ (lr & 7)) * 8)]);
      bf16x8 v1 = *(const bf16x8*)(&Vs[p][(jf * 16 + lr) * 64 + (((4 + g) ^ (lr & 7)) * 8)]);
      acc[jf] = __builtin_amdgcn_mfma_f32_16x16x32_bf16(pa0, v0, acc[jf], 0, 0, 0);
      acc[jf] = __builtin_amdgcn_mfma_f32_16x16x32_bf16(pa1, v1, acc[jf], 0, 0, 0);
    }
    __builtin_amdgcn_s_setprio(0);

    BAR_LGKM();
  }
#undef STAGE

  const int h = bh & 15;
  float rl[4];
#pragma unroll
  for (int r = 0; r < 4; ++r) rl[r] = __builtin_amdgcn_rcpf(accl[r]);
#pragma unroll
  for (int jf = 0; jf < 8; ++jf)
#pragma unroll
    for (int r = 0; r < 4; ++r) {
      int tt = qb + w * 16 + g * 4 + r;
      Yg[((size_t)b * 2048 + tt) * 2048 + h * 128 + jf * 16 + lr] = f2bf(acc[jf][r] * rl[r]);
    }
}

// ---------------- launch ----------------
extern "C" void kernel_launch(void* const* d_in, const int* in_sizes, int n_in, void* d_out,
                              int out_size, void* d_ws, size_t ws_size, hipStream_t stream) {
  const float* x = (const float*)d_in[0];
  const unsigned char* amask = (const unsigned char*)d_in[1];
  const int* iscausal = (const int*)d_in[2];
  const float* wqkv = (const float*)d_in[3];
  const float* wout = (const float*)d_in[4];
  float* out = (float*)d_out;

  const size_t MT = 8192, D = 2048, ND = 6144;
  unsigned short* xb = (unsigned short*)d_ws;
  unsigned short* wqkvb = xb + MT * D;
  unsigned short* woutb = wqkvb + ND * D;
  unsigned short* q = woutb + D * D;
  unsigned short* k = q + MT * D;
  unsigned short* vt = k + MT * D;
  unsigned short* y = vt + MT * D;
  float* tab = (float*)(y + MT * D);
  if (ws_size < (size_t)(100663296) * 2 + 2048 * 128 * 4) return;

  cvt_bf16<<<dim3(16384), dim3(256), 0, stream>>>(x, xb, (int)(MT * D));
  cvt_bf16<<<dim3(12288), dim3(256), 0, stream>>>(wqkv, wqkvb, (int)(ND * D));
  cvt_bf16<<<dim3(4096), dim3(256), 0, stream>>>(wout, woutb, (int)(D * D));
  rope_table<<<dim3(512), dim3(256), 0, stream>>>(tab);
  gemm256<1><<<dim3(24, 32), dim3(512), 0, stream>>>(xb, wqkvb, nullptr, 8192, 6144, 2048, q, k, vt);
  rope_apply<<<dim3(8192), dim3(256), 0, stream>>>(q, k, tab);
  flash_attn<<<dim3(2048), dim3(256), 0, stream>>>(q, k, vt, y, iscausal, amask);
  gemm256<0><<<dim3(8, 32), dim3(512), 0, stream>>>(y, woutb, out, 8192, 2048, 2048, nullptr,
                                                    nullptr, nullptr);
}

// Round 11
// 500.368 us; speedup vs baseline: 1.9511x; 1.0371x over previous
//
#include <hip/hip_runtime.h>
#include <stdint.h>
#include <stddef.h>

typedef float f32x4 __attribute__((ext_vector_type(4)));
typedef __bf16 bf16x8 __attribute__((ext_vector_type(8)));
typedef short s16x4 __attribute__((ext_vector_type(4)));

#define DEVI static __device__ __forceinline__

DEVI float bf2f(unsigned short u) {
  unsigned int x = ((unsigned int)u) << 16;
  float f;
  __builtin_memcpy(&f, &x, 4);
  return f;
}
DEVI unsigned short f2bf(float f) {
  unsigned int x;
  __builtin_memcpy(&x, &f, 4);
  unsigned int r = (x + 0x7fffu + ((x >> 16) & 1u)) >> 16;
  return (unsigned short)r;
}

DEVI void async16(const void* g, void* l) {
  __builtin_amdgcn_global_load_lds((__attribute__((address_space(1))) void*)g,
                                   (__attribute__((address_space(3))) void*)l,
                                   16, 0, 0);
}

// raw barrier with own-LDS-ops drain; vmcnt NOT touched.
#define BAR_LGKM()                                          \
  do {                                                      \
    asm volatile("s_waitcnt lgkmcnt(0)" ::: "memory");      \
    __builtin_amdgcn_s_barrier();                           \
    __builtin_amdgcn_sched_barrier(0);                      \
  } while (0)

// counted-vmcnt barrier: N loads may stay in flight (T4).
#define BAR_VM(N)                                               \
  do {                                                          \
    asm volatile("s_waitcnt vmcnt(" #N ")" ::: "memory");       \
    __builtin_amdgcn_s_barrier();                               \
    __builtin_amdgcn_sched_barrier(0);                          \
  } while (0)

// ---------------- fp32 -> bf16 conversion ----------------
__global__ __launch_bounds__(256) void cvt_bf16(const float* __restrict__ in,
                                                unsigned short* __restrict__ out, int n) {
  int i = (blockIdx.x * 256 + threadIdx.x) * 4;
  if (i >= n) return;
  float4 v = *(const float4*)(in + i);
  s16x4 o;
  o[0] = (short)f2bf(v.x);
  o[1] = (short)f2bf(v.y);
  o[2] = (short)f2bf(v.z);
  o[3] = (short)f2bf(v.w);
  *(s16x4*)(out + i) = o;
}

// ---------------- RoPE table: tab[t][0..63]=cos, tab[t][64..127]=sin ----------------
__global__ __launch_bounds__(256) void rope_table(float* __restrict__ tab) {
  int idx = blockIdx.x * 256 + threadIdx.x;
  if (idx >= 2048 * 64) return;
  int tt = idx >> 6, j = idx & 63;
  float inv = powf(10000.0f, -(float)j * (1.0f / 64.0f));
  float ang = (float)tt * inv;
  tab[tt * 128 + j] = cosf(ang);
  tab[tt * 128 + 64 + j] = sinf(ang);
}

// ---------------- RoPE apply, vectorized x4; Q pre-scaled by 1/sqrt(hd)*log2(e) ----
__global__ __launch_bounds__(256) void rope_apply(unsigned short* __restrict__ Qg,
                                                  unsigned short* __restrict__ Kg,
                                                  const float* __restrict__ tab) {
  const float S2 = 0.0883883476483184f * 1.44269504088896341f;
  int idx = blockIdx.x * 256 + threadIdx.x;  // bh*2048*16 + tt*16 + j4
  int j4 = idx & 15;
  int tt = (idx >> 4) & 2047;
  int bh = idx >> 15;
  size_t base = ((size_t)bh * 2048 + tt) * 128;
  f32x4 c4 = *(const f32x4*)(tab + tt * 128 + j4 * 4);
  f32x4 s4 = *(const f32x4*)(tab + tt * 128 + 64 + j4 * 4);
  s16x4 q1 = *(const s16x4*)(Qg + base + j4 * 4);
  s16x4 q2 = *(const s16x4*)(Qg + base + 64 + j4 * 4);
  s16x4 k1 = *(const s16x4*)(Kg + base + j4 * 4);
  s16x4 k2 = *(const s16x4*)(Kg + base + 64 + j4 * 4);
  s16x4 o1, o2, p1, p2;
#pragma unroll
  for (int r = 0; r < 4; ++r) {
    float c = c4[r], s = s4[r];
    float a = bf2f((unsigned short)q1[r]), b2 = bf2f((unsigned short)q2[r]);
    o1[r] = (short)f2bf((a * c - b2 * s) * S2);
    o2[r] = (short)f2bf((a * s + b2 * c) * S2);
    float ka = bf2f((unsigned short)k1[r]), kb = bf2f((unsigned short)k2[r]);
    p1[r] = (short)f2bf(ka * c - kb * s);
    p2[r] = (short)f2bf(ka * s + kb * c);
  }
  *(s16x4*)(Qg + base + j4 * 4) = o1;
  *(s16x4*)(Qg + base + 64 + j4 * 4) = o2;
  *(s16x4*)(Kg + base + j4 * 4) = p1;
  *(s16x4*)(Kg + base + 64 + j4 * 4) = p2;
}

// ---------------- 256x256 8-phase GEMM: C[m][n] = sum_k A[m][k]*B[n][k] ----------------
// R11: race-free rework of R10. Quad order per tile: (mh0,nh0)->(mh1,nh0)->
// (mh1,nh1)->(mh0,nh1): B held in regs across pairs, A quarter-0 RE-READ from
// LDS at phase 3 (re-reads are safe; only stores race). Region free windows:
// Bl[p] free after phase2 of its tile, Al[p] free after phase3. Stage slots
// strictly inside free windows: r0: A(1,h0+h1,t1); r3: B(0,h0,t2); r4:
// B(0,h1,t2); r5: A(0,h0,t2); r6: A(0,h1,t2); r7: B(1,h0+h1,t3). FIFO: vmcnt(2)
// @r3 (all 8 of t1 landed before r4 reads), vmcnt(4) @r7 (all of t2 before
// next r0). gemm_bt's measured-zero-conflict layout: 128B rows, unit swizzle
// (t&7)^(row&7) on both sides.
template <int EPI>
__global__ __launch_bounds__(512) void gemm256(const unsigned short* __restrict__ A,
                                               const unsigned short* __restrict__ B,
                                               float* __restrict__ C, int M, int N, int K,
                                               unsigned short* __restrict__ Q,
                                               unsigned short* __restrict__ Kk,
                                               unsigned short* __restrict__ VT) {
  __shared__ __attribute__((aligned(128))) unsigned short Al[2][2][8192];
  __shared__ __attribute__((aligned(128))) unsigned short Bl[2][2][8192];
  const int t = threadIdx.x;
  const int lane = t & 63;
  const int w = t >> 6, wr = w >> 2, wc = w & 3;
  const int g = lane >> 4, lr = lane & 15;

  const int id = blockIdx.y * gridDim.x + blockIdx.x;
  const int nwg = gridDim.x * gridDim.y;
  const int wg = (id & 7) * (nwg >> 3) + (id >> 3);  // XCD-chunked (nwg%8==0)
  const int bm = (wg / gridDim.x) * 256, bn = (wg % gridDim.x) * 256;

  const unsigned short* aptr = A + (size_t)bm * K;
  const unsigned short* bptr = B + (size_t)bn * K;

  const int srow = t >> 3;                 // 0..63
  const int sslot = (t & 7) ^ (srow & 7);  // inverse-swizzled source 16B slot

  // stage half-tile (mat, p, h): rows h*128+srow and +64; dest unit t&7 of row.
#define STG(arr, mat, p, h, kt)                                                   \
  do {                                                                            \
    const unsigned short* _s =                                                    \
        (mat) + (size_t)((h) * 128 + srow) * K + (size_t)(kt) * 64 + sslot * 8;   \
    async16(_s, &arr[p][h][t * 8]);                                               \
    async16(_s + (size_t)64 * K, &arr[p][h][t * 8 + 4096]);                       \
  } while (0)

  // frag reads: row r (=16*base+lr) at r*64 shorts; unit (kk*4+g)^(lr&7).
  const int u0 = ((g ^ (lr & 7)) * 8) + lr * 64;
  const int u1 = (((4 + g) ^ (lr & 7)) * 8) + lr * 64;

#define LDA(p, mh)                                                                \
  _Pragma("unroll") for (int mf = 0; mf < 4; ++mf) {                              \
    af[mf][0] = *(const bf16x8*)&Al[p][wr][(mh) * 4096 + mf * 1024 + u0];         \
    af[mf][1] = *(const bf16x8*)&Al[p][wr][(mh) * 4096 + mf * 1024 + u1];         \
  }
#define LDB(p, nh)                                                                \
  _Pragma("unroll") for (int nf = 0; nf < 2; ++nf) {                              \
    bfr[nf][0] = *(const bf16x8*)&Bl[p][wc >> 1][(wc & 1) * 4096 + (nh) * 2048 +  \
                                                 nf * 1024 + u0];                 \
    bfr[nf][1] = *(const bf16x8*)&Bl[p][wc >> 1][(wc & 1) * 4096 + (nh) * 2048 +  \
                                                 nf * 1024 + u1];                 \
  }
#define MMA(mh, nh)                                                               \
  __builtin_amdgcn_s_setprio(1);                                                  \
  _Pragma("unroll") for (int mf = 0; mf < 4; ++mf)                                \
      _Pragma("unroll") for (int nf = 0; nf < 2; ++nf) {                          \
    acc[(mh) * 4 + mf][(nh) * 2 + nf] = __builtin_amdgcn_mfma_f32_16x16x32_bf16(  \
        af[mf][0], bfr[nf][0], acc[(mh) * 4 + mf][(nh) * 2 + nf], 0, 0, 0);       \
    acc[(mh) * 4 + mf][(nh) * 2 + nf] = __builtin_amdgcn_mfma_f32_16x16x32_bf16(  \
        af[mf][1], bfr[nf][1], acc[(mh) * 4 + mf][(nh) * 2 + nf], 0, 0, 0);       \
  }                                                                               \
  __builtin_amdgcn_s_setprio(0);
#define PH_PRE()                                           \
  do {                                                     \
    __builtin_amdgcn_s_barrier();                          \
    asm volatile("s_waitcnt lgkmcnt(0)" ::: "memory");     \
    __builtin_amdgcn_sched_barrier(0);                     \
  } while (0)
#define PH_POST() __builtin_amdgcn_s_barrier();

  f32x4 acc[8][4] = {};

  // prologue: tile0's 4 halves (8 loads, oldest), then t1's B halves (4 loads).
  STG(Al, aptr, 0, 0, 0);
  STG(Al, aptr, 0, 1, 0);
  STG(Bl, bptr, 0, 0, 0);
  STG(Bl, bptr, 0, 1, 0);
  STG(Bl, bptr, 1, 0, 1);
  STG(Bl, bptr, 1, 1, 1);
  asm volatile("s_waitcnt vmcnt(4)" ::: "memory");  // tile0's 8 loads landed
  __builtin_amdgcn_s_barrier();
  __builtin_amdgcn_sched_barrier(0);

  const int NITER = K >> 7;
  for (int i = 0; i < NITER; ++i) {
    const bool G = (i + 1 < NITER);
    const int t1 = 2 * i + 1, t2 = 2 * i + 2, t3 = 2 * i + 3;
    bf16x8 af[4][2], bfr[2][2];

    // r0: tile(p0) quad(mh0,nh0); stage t1's A (both halves; regions free since
    // prev r7's barrier; landing guaranteed by r3's vmcnt before r4 reads)
    LDA(0, 0);
    LDB(0, 0);
    STG(Al, aptr, 1, 0, t1);
    STG(Al, aptr, 1, 1, t1);
    PH_PRE();
    MMA(0, 0);
    PH_POST();
    // r1: quad(mh1,nh0), B reused in regs
    LDA(0, 1);
    PH_PRE();
    MMA(1, 0);
    PH_POST();
    // r2: quad(mh1,nh1), A reused in regs
    LDB(0, 1);
    PH_PRE();
    MMA(1, 1);
    PH_POST();
    // r3: quad(mh0,nh1), A q0 re-read; stage B(0,h0,t2) (Bl[0] free after r2);
    // vmcnt(2): drains prev-r7's B(t1) + r0's A(t1) -> t1 complete before r4.
    LDA(0, 0);
    if (G) {
      STG(Bl, bptr, 0, 0, t2);
      asm volatile("s_waitcnt vmcnt(2)" ::: "memory");
    } else {
      asm volatile("s_waitcnt vmcnt(0)" ::: "memory");
    }
    PH_PRE();
    MMA(0, 1);
    PH_POST();
    // r4: tile(p1) quad(mh0,nh0); stage B(0,h1,t2)
    LDA(1, 0);
    LDB(1, 0);
    if (G) STG(Bl, bptr, 0, 1, t2);
    PH_PRE();
    MMA(0, 0);
    PH_POST();
    // r5: quad(mh1,nh0); stage A(0,h0,t2) (Al[0] free after r3)
    LDA(1, 1);
    if (G) STG(Al, aptr, 0, 0, t2);
    PH_PRE();
    MMA(1, 0);
    PH_POST();
    // r6: quad(mh1,nh1); stage A(0,h1,t2)
    LDB(1, 1);
    if (G) STG(Al, aptr, 0, 1, t2);
    PH_PRE();
    MMA(1, 1);
    PH_POST();
    // r7: quad(mh0,nh1), A q0 re-read; stage B(1,both,t3) (Bl[1] free after r6);
    // vmcnt(4): drains t2's 8 loads (r3..r6) before next r0 reads them.
    LDA(1, 0);
    if (G) {
      STG(Bl, bptr, 1, 0, t3);
      STG(Bl, bptr, 1, 1, t3);
      asm volatile("s_waitcnt vmcnt(4)" ::: "memory");
    }
    PH_PRE();
    MMA(0, 1);
    PH_POST();
  }
#undef STG
#undef LDA
#undef LDB
#undef MMA
#undef PH_PRE
#undef PH_POST

  // epilogue: acc[mh*4+mf][nh*2+nf]: row off = (mp>>2)*64+(mp&3)*16+g*4,
  // col off = (nfi>>1)*32 + (nfi&1)*16 + lr.
  if (EPI == 0) {
#pragma unroll
    for (int mp = 0; mp < 8; ++mp) {
      int m0 = bm + wr * 128 + (mp >> 2) * 64 + (mp & 3) * 16 + g * 4;
#pragma unroll
      for (int nfi = 0; nfi < 4; ++nfi) {
        int n = bn + wc * 64 + (nfi >> 1) * 32 + (nfi & 1) * 16 + lr;
#pragma unroll
        for (int r = 0; r < 4; ++r) C[(size_t)(m0 + r) * N + n] = acc[mp][nfi][r];
      }
    }
  } else {
    const int bi = bm >> 11;
    const int tbase = bm & 2047;
#pragma unroll
    for (int nfi = 0; nfi < 4; ++nfi) {
      int e = bn + wc * 64 + (nfi >> 1) * 32 + (nfi & 1) * 16 + lr;  // region uniform/block
      int region = e >> 11;
      int e2 = e & 2047;
      int h = e2 >> 7, d = e2 & 127;
      int bh = bi * 16 + h;
#pragma unroll
      for (int mp = 0; mp < 8; ++mp) {
        int trow = tbase + wr * 128 + (mp >> 2) * 64 + (mp & 3) * 16 + g * 4;
        if (region == 2) {
          s16x4 pk;
#pragma unroll
          for (int r = 0; r < 4; ++r) pk[r] = (short)f2bf(acc[mp][nfi][r]);
          *(s16x4*)(VT + ((size_t)bh * 128 + d) * 2048 + trow) = pk;
        } else {
          unsigned short* dst = (region == 0) ? Q : Kk;
#pragma unroll
          for (int r = 0; r < 4; ++r)
            dst[((size_t)bh * 2048 + trow + r) * 128 + d] = f2bf(acc[mp][nfi][r]);
        }
      }
    }
  }
}

// ---------------- flash attention (R8, unchanged) ----------------
__global__ __launch_bounds__(256) void flash_attn(const unsigned short* __restrict__ Qg,
                                                  const unsigned short* __restrict__ Kg,
                                                  const unsigned short* __restrict__ VTg,
                                                  unsigned short* __restrict__ Yg,
                                                  const int* __restrict__ iscausal,
                                                  const unsigned char* __restrict__ amask) {
  __shared__ __attribute__((aligned(128))) unsigned short Ks[2][64 * 128];
  __shared__ __attribute__((aligned(128))) unsigned short Vs[2][128 * 64];
  __shared__ __attribute__((aligned(128))) unsigned short Ps[4][16 * 72];

  const int t = threadIdx.x, lane = t & 63, w = t >> 6;
  const int g = lane >> 4, lr = lane & 15;
  const int id = blockIdx.x;
  const int xcd = id & 7, j5 = id >> 3;
  const int bh = xcd * 8 + (j5 >> 5);
  const int qbi = 31 - (j5 & 31);
  const int b = bh >> 4;
  const int qb = qbi * 64;
  const int causal = iscausal[0] != 0;
  const int nt = causal ? (qbi + 1) : 32;

  const unsigned short* qrow = Qg + ((size_t)bh * 2048 + qb + w * 16 + lr) * 128;
  bf16x8 qf[4];
#pragma unroll
  for (int ds = 0; ds < 4; ++ds) qf[ds] = *(const bf16x8*)(qrow + ds * 32 + g * 8);

  const unsigned short* Kbase = Kg + (size_t)bh * 2048 * 128;
  const unsigned short* Vbase = VTg + (size_t)bh * 128 * 2048;

  const int rK = t >> 4, sK = ((t & 15) ^ rK);
  const int rV = t >> 3, sV = ((t & 7) ^ ((t >> 3) & 7));

#define STAGE(KT, P)                                                                    \
  do {                                                                                  \
    const int _kv = (KT) * 64;                                                          \
    _Pragma("unroll") for (int c = 0; c < 4; ++c)                                       \
        async16(Kbase + (size_t)(_kv + c * 16 + rK) * 128 + sK * 8,                     \
                &Ks[P][c * 2048 + t * 8]);                                              \
    _Pragma("unroll") for (int c = 0; c < 4; ++c)                                       \
        async16(Vbase + (size_t)(c * 32 + rV) * 2048 + _kv + sV * 8,                    \
                &Vs[P][c * 2048 + t * 8]);                                              \
  } while (0)

  unsigned int oi[4] = {0x3F803F80u, 0x3F803F80u, 0x3F803F80u, 0x3F803F80u};
  bf16x8 ones;
  __builtin_memcpy(&ones, oi, 16);

  f32x4 acc[8] = {};
  f32x4 accl = {0.f, 0.f, 0.f, 0.f};
  float mrow[4] = {-1e30f, -1e30f, -1e30f, -1e30f};

  STAGE(0, 0);

  for (int kt = 0; kt < nt; ++kt) {
    const int p = kt & 1;
    const int kv0 = kt * 64;
    if (kt + 1 < nt) {
      STAGE(kt + 1, p ^ 1);
      BAR_VM(8);
    } else {
      BAR_VM(0);
    }

    f32x4 s[4] = {};
    __builtin_amdgcn_s_setprio(1);
#pragma unroll
    for (int cf = 0; cf < 4; ++cf)
#pragma unroll
      for (int ds = 0; ds < 4; ++ds) {
        bf16x8 kf = *(const bf16x8*)(&Ks[p][(cf * 16 + lr) * 128 + (((ds * 4 + g) ^ lr) * 8)]);
        s[cf] = __builtin_amdgcn_mfma_f32_16x16x32_bf16(qf[ds], kf, s[cf], 0, 0, 0);
      }
    __builtin_amdgcn_s_setprio(0);

    const int q0 = qb + w * 16 + g * 4;
    if (causal) {
      if (kt == qbi) {
#pragma unroll
        for (int cf = 0; cf < 4; ++cf) {
          int kvg = kv0 + cf * 16 + lr;
#pragma unroll
          for (int r = 0; r < 4; ++r)
            if (kvg > q0 + r) s[cf][r] = -1e30f;
        }
      }
    } else {
#pragma unroll
      for (int cf = 0; cf < 4; ++cf) {
        int kvg = kv0 + cf * 16 + lr;
        if (!amask[(size_t)b * 2048 + kvg]) {
#pragma unroll
          for (int r = 0; r < 4; ++r) s[cf][r] = -1e30f;
        }
      }
    }

    f32x4 lm;
#pragma unroll
    for (int r = 0; r < 4; ++r)
      lm[r] = fmaxf(fmaxf(s[0][r], s[1][r]), fmaxf(s[2][r], s[3][r]));
    bool ok = true;
#pragma unroll
    for (int r = 0; r < 4; ++r) ok = ok && (lm[r] <= mrow[r] + 8.0f);
    if (!__all(ok)) {
      f32x4 mx = lm;
#pragma unroll
      for (int off = 8; off >= 1; off >>= 1)
#pragma unroll
        for (int r = 0; r < 4; ++r) mx[r] = fmaxf(mx[r], __shfl_xor(mx[r], off));
#pragma unroll
      for (int r = 0; r < 4; ++r) {
        float mn = fmaxf(mrow[r], mx[r]);
        float corr = exp2f(mrow[r] - mn);
        mrow[r] = mn;
        accl[r] *= corr;
#pragma unroll
        for (int jf = 0; jf < 8; ++jf) acc[jf][r] *= corr;
      }
    }

#pragma unroll
    for (int cf = 0; cf < 4; ++cf)
#pragma unroll
      for (int r = 0; r < 4; ++r) s[cf][r] = exp2f(s[cf][r] - mrow[r]);

    unsigned short* Pw = &Ps[w][0];
#pragma unroll
    for (int cf = 0; cf < 4; ++cf)
#pragma unroll
      for (int r = 0; r < 4; ++r) Pw[(g * 4 + r) * 72 + cf * 16 + lr] = f2bf(s[cf][r]);
    asm volatile("s_waitcnt lgkmcnt(0)" ::: "memory");
    __builtin_amdgcn_sched_barrier(0);

    bf16x8 pa0 = *(const bf16x8*)(Pw + lr * 72 + g * 8);
    bf16x8 pa1 = *(const bf16x8*)(Pw + lr * 72 + 32 + g * 8);

    accl = __builtin_amdgcn_mfma_f32_16x16x32_bf16(pa0, ones, accl, 0, 0, 0);
    accl = __builtin_amdgcn_mfma_f32_16x16x32_bf16(pa1, ones, accl, 0, 0, 0);

    __builtin_amdgcn_s_setprio(1);
#pragma unroll
    for (int jf = 0; jf < 8; ++jf) {
      bf16x8 v0 = *(const bf16x8*)(&Vs[p][(jf * 16 + lr) * 64 + ((g ^ (lr & 7)) * 8)]);
      bf16x8 v1 = *(const bf16x8*)(&Vs[p][(jf * 16 + lr) * 64 + (((4 + g) ^ (lr & 7)) * 8)]);
      acc[jf] = __builtin_amdgcn_mfma_f32_16x16x32_bf16(pa0, v0, acc[jf], 0, 0, 0);
      acc[jf] = __builtin_amdgcn_mfma_f32_16x16x32_bf16(pa1, v1, acc[jf], 0, 0, 0);
    }
    __builtin_amdgcn_s_setprio(0);

    BAR_LGKM();
  }
#undef STAGE

  const int h = bh & 15;
  float rl[4];
#pragma unroll
  for (int r = 0; r < 4; ++r) rl[r] = __builtin_amdgcn_rcpf(accl[r]);
#pragma unroll
  for (int jf = 0; jf < 8; ++jf)
#pragma unroll
    for (int r = 0; r < 4; ++r) {
      int tt = qb + w * 16 + g * 4 + r;
      Yg[((size_t)b * 2048 + tt) * 2048 + h * 128 + jf * 16 + lr] = f2bf(acc[jf][r] * rl[r]);
    }
}

// ---------------- launch ----------------
extern "C" void kernel_launch(void* const* d_in, const int* in_sizes, int n_in, void* d_out,
                              int out_size, void* d_ws, size_t ws_size, hipStream_t stream) {
  const float* x = (const float*)d_in[0];
  const unsigned char* amask = (const unsigned char*)d_in[1];
  const int* iscausal = (const int*)d_in[2];
  const float* wqkv = (const float*)d_in[3];
  const float* wout = (const float*)d_in[4];
  float* out = (float*)d_out;

  const size_t MT = 8192, D = 2048, ND = 6144;
  unsigned short* xb = (unsigned short*)d_ws;
  unsigned short* wqkvb = xb + MT * D;
  unsigned short* woutb = wqkvb + ND * D;
  unsigned short* q = woutb + D * D;
  unsigned short* k = q + MT * D;
  unsigned short* vt = k + MT * D;
  unsigned short* y = vt + MT * D;
  float* tab = (float*)(y + MT * D);
  if (ws_size < (size_t)(100663296) * 2 + 2048 * 128 * 4) return;

  cvt_bf16<<<dim3(16384), dim3(256), 0, stream>>>(x, xb, (int)(MT * D));
  cvt_bf16<<<dim3(12288), dim3(256), 0, stream>>>(wqkv, wqkvb, (int)(ND * D));
  cvt_bf16<<<dim3(4096), dim3(256), 0, stream>>>(wout, woutb, (int)(D * D));
  rope_table<<<dim3(512), dim3(256), 0, stream>>>(tab);
  gemm256<1><<<dim3(24, 32), dim3(512), 0, stream>>>(xb, wqkvb, nullptr, 8192, 6144, 2048, q, k, vt);
  rope_apply<<<dim3(8192), dim3(256), 0, stream>>>(q, k, tab);
  flash_attn<<<dim3(2048), dim3(256), 0, stream>>>(q, k, vt, y, iscausal, amask);
  gemm256<0><<<dim3(8, 32), dim3(512), 0, stream>>>(y, woutb, out, 8192, 2048, 2048, nullptr,
                                                    nullptr, nullptr);
}

// Round 12
// 484.996 us; speedup vs baseline: 2.0130x; 1.0317x over previous
//
#include <hip/hip_runtime.h>
#include <stdint.h>
#include <stddef.h>

typedef float f32x4 __attribute__((ext_vector_type(4)));
typedef __bf16 bf16x8 __attribute__((ext_vector_type(8)));
typedef short s16x4 __attribute__((ext_vector_type(4)));

#define DEVI static __device__ __forceinline__

DEVI float bf2f(unsigned short u) {
  unsigned int x = ((unsigned int)u) << 16;
  float f;
  __builtin_memcpy(&f, &x, 4);
  return f;
}
DEVI unsigned short f2bf(float f) {
  unsigned int x;
  __builtin_memcpy(&x, &f, 4);
  unsigned int r = (x + 0x7fffu + ((x >> 16) & 1u)) >> 16;
  return (unsigned short)r;
}

DEVI void async16(const void* g, void* l) {
  __builtin_amdgcn_global_load_lds((__attribute__((address_space(1))) void*)g,
                                   (__attribute__((address_space(3))) void*)l,
                                   16, 0, 0);
}

// raw barrier with own-LDS-ops drain; vmcnt NOT touched.
#define BAR_LGKM()                                          \
  do {                                                      \
    asm volatile("s_waitcnt lgkmcnt(0)" ::: "memory");      \
    __builtin_amdgcn_s_barrier();                           \
    __builtin_amdgcn_sched_barrier(0);                      \
  } while (0)

// counted-vmcnt barrier: N loads may stay in flight (T4).
#define BAR_VM(N)                                               \
  do {                                                          \
    asm volatile("s_waitcnt vmcnt(" #N ")" ::: "memory");       \
    __builtin_amdgcn_s_barrier();                               \
    __builtin_amdgcn_sched_barrier(0);                          \
  } while (0)

// ---------------- fp32 -> bf16 conversion ----------------
__global__ __launch_bounds__(256) void cvt_bf16(const float* __restrict__ in,
                                                unsigned short* __restrict__ out, int n) {
  int i = (blockIdx.x * 256 + threadIdx.x) * 4;
  if (i >= n) return;
  float4 v = *(const float4*)(in + i);
  s16x4 o;
  o[0] = (short)f2bf(v.x);
  o[1] = (short)f2bf(v.y);
  o[2] = (short)f2bf(v.z);
  o[3] = (short)f2bf(v.w);
  *(s16x4*)(out + i) = o;
}

// ---------------- RoPE table: tab[t][0..63]=cos, tab[t][64..127]=sin ----------------
__global__ __launch_bounds__(256) void rope_table(float* __restrict__ tab) {
  int idx = blockIdx.x * 256 + threadIdx.x;
  if (idx >= 2048 * 64) return;
  int tt = idx >> 6, j = idx & 63;
  float inv = powf(10000.0f, -(float)j * (1.0f / 64.0f));
  float ang = (float)tt * inv;
  tab[tt * 128 + j] = cosf(ang);
  tab[tt * 128 + 64 + j] = sinf(ang);
}

// ---------------- RoPE apply, vectorized x4; Q pre-scaled by 1/sqrt(hd)*log2(e) ----
__global__ __launch_bounds__(256) void rope_apply(unsigned short* __restrict__ Qg,
                                                  unsigned short* __restrict__ Kg,
                                                  const float* __restrict__ tab) {
  const float S2 = 0.0883883476483184f * 1.44269504088896341f;
  int idx = blockIdx.x * 256 + threadIdx.x;  // bh*2048*16 + tt*16 + j4
  int j4 = idx & 15;
  int tt = (idx >> 4) & 2047;
  int bh = idx >> 15;
  size_t base = ((size_t)bh * 2048 + tt) * 128;
  f32x4 c4 = *(const f32x4*)(tab + tt * 128 + j4 * 4);
  f32x4 s4 = *(const f32x4*)(tab + tt * 128 + 64 + j4 * 4);
  s16x4 q1 = *(const s16x4*)(Qg + base + j4 * 4);
  s16x4 q2 = *(const s16x4*)(Qg + base + 64 + j4 * 4);
  s16x4 k1 = *(const s16x4*)(Kg + base + j4 * 4);
  s16x4 k2 = *(const s16x4*)(Kg + base + 64 + j4 * 4);
  s16x4 o1, o2, p1, p2;
#pragma unroll
  for (int r = 0; r < 4; ++r) {
    float c = c4[r], s = s4[r];
    float a = bf2f((unsigned short)q1[r]), b2 = bf2f((unsigned short)q2[r]);
    o1[r] = (short)f2bf((a * c - b2 * s) * S2);
    o2[r] = (short)f2bf((a * s + b2 * c) * S2);
    float ka = bf2f((unsigned short)k1[r]), kb = bf2f((unsigned short)k2[r]);
    p1[r] = (short)f2bf(ka * c - kb * s);
    p2[r] = (short)f2bf(ka * s + kb * c);
  }
  *(s16x4*)(Qg + base + j4 * 4) = o1;
  *(s16x4*)(Qg + base + 64 + j4 * 4) = o2;
  *(s16x4*)(Kg + base + j4 * 4) = p1;
  *(s16x4*)(Kg + base + 64 + j4 * 4) = p2;
}

// ---------------- 256x256 8-phase GEMM: C[m][n] = sum_k A[m][k]*B[n][k] ----------------
// R12: (a) quad order (0,0)->(0,1)->(1,1)->(1,0) with TWO persistent B-frag sets
// (bfrA=nh0, bfrB=nh1) and one A set -> r3/r7 have ZERO ds_reads (stage+vmcnt+
// MFMA only); 48 ds_reads/iter vs R11's 64. (b) phase entry is s_barrier ONLY:
// no forced lgkmcnt(0)/sched_barrier -> compiler emits fine-grained lgkmcnt(N)
// so early MFMAs overlap late ds_read returns. vmcnt asm (the one ordering the
// compiler can't see: global_load_lds -> ds_read) kept at r3/r7/prologue.
// Region lifetimes: Bl[p] free after r1, Al[p] after r2; stages at r0(A t1),
// r3/r4(B t2), r5/r6(A t2), r7(B t3); vmcnt(2)@r3 drains t1's 8, vmcnt(4)@r7
// drains t2's 8. Layout: 128B rows, unit swizzle (t&7)^(row&7) both sides
// (measured 0 conflicts).
template <int EPI>
__global__ __launch_bounds__(512) void gemm256(const unsigned short* __restrict__ A,
                                               const unsigned short* __restrict__ B,
                                               float* __restrict__ C, int M, int N, int K,
                                               unsigned short* __restrict__ Q,
                                               unsigned short* __restrict__ Kk,
                                               unsigned short* __restrict__ VT) {
  __shared__ __attribute__((aligned(128))) unsigned short Al[2][2][8192];
  __shared__ __attribute__((aligned(128))) unsigned short Bl[2][2][8192];
  const int t = threadIdx.x;
  const int lane = t & 63;
  const int w = t >> 6, wr = w >> 2, wc = w & 3;
  const int g = lane >> 4, lr = lane & 15;

  const int id = blockIdx.y * gridDim.x + blockIdx.x;
  const int nwg = gridDim.x * gridDim.y;
  const int wg = (id & 7) * (nwg >> 3) + (id >> 3);  // XCD-chunked (nwg%8==0)
  const int bm = (wg / gridDim.x) * 256, bn = (wg % gridDim.x) * 256;

  const unsigned short* aptr = A + (size_t)bm * K;
  const unsigned short* bptr = B + (size_t)bn * K;

  const int srow = t >> 3;                 // 0..63
  const int sslot = (t & 7) ^ (srow & 7);  // inverse-swizzled source 16B slot

#define STG(arr, mat, p, h, kt)                                                   \
  do {                                                                            \
    const unsigned short* _s =                                                    \
        (mat) + (size_t)((h) * 128 + srow) * K + (size_t)(kt) * 64 + sslot * 8;   \
    async16(_s, &arr[p][h][t * 8]);                                               \
    async16(_s + (size_t)64 * K, &arr[p][h][t * 8 + 4096]);                       \
  } while (0)

  const int u0 = ((g ^ (lr & 7)) * 8) + lr * 64;
  const int u1 = (((4 + g) ^ (lr & 7)) * 8) + lr * 64;

#define LDA_(p, mh)                                                               \
  _Pragma("unroll") for (int mf = 0; mf < 4; ++mf) {                              \
    af[mf][0] = *(const bf16x8*)&Al[p][wr][(mh) * 4096 + mf * 1024 + u0];         \
    af[mf][1] = *(const bf16x8*)&Al[p][wr][(mh) * 4096 + mf * 1024 + u1];         \
  }
#define LDB_(dst, p, nh)                                                          \
  _Pragma("unroll") for (int nf = 0; nf < 2; ++nf) {                              \
    dst[nf][0] = *(const bf16x8*)&Bl[p][wc >> 1][(wc & 1) * 4096 + (nh) * 2048 +  \
                                                 nf * 1024 + u0];                 \
    dst[nf][1] = *(const bf16x8*)&Bl[p][wc >> 1][(wc & 1) * 4096 + (nh) * 2048 +  \
                                                 nf * 1024 + u1];                 \
  }
#define MMA_(bsrc, mh, nh)                                                        \
  __builtin_amdgcn_s_setprio(1);                                                  \
  _Pragma("unroll") for (int mf = 0; mf < 4; ++mf)                                \
      _Pragma("unroll") for (int nf = 0; nf < 2; ++nf) {                          \
    acc[(mh) * 4 + mf][(nh) * 2 + nf] = __builtin_amdgcn_mfma_f32_16x16x32_bf16(  \
        af[mf][0], bsrc[nf][0], acc[(mh) * 4 + mf][(nh) * 2 + nf], 0, 0, 0);      \
    acc[(mh) * 4 + mf][(nh) * 2 + nf] = __builtin_amdgcn_mfma_f32_16x16x32_bf16(  \
        af[mf][1], bsrc[nf][1], acc[(mh) * 4 + mf][(nh) * 2 + nf], 0, 0, 0);      \
  }                                                                               \
  __builtin_amdgcn_s_setprio(0);
#define BARR() __builtin_amdgcn_s_barrier();

  f32x4 acc[8][4] = {};
  bf16x8 af[4][2], bfrA[2][2], bfrB[2][2];

  // prologue: tile0's 4 halves (8 loads, oldest), then t1's B halves (4 loads).
  STG(Al, aptr, 0, 0, 0);
  STG(Al, aptr, 0, 1, 0);
  STG(Bl, bptr, 0, 0, 0);
  STG(Bl, bptr, 0, 1, 0);
  STG(Bl, bptr, 1, 0, 1);
  STG(Bl, bptr, 1, 1, 1);
  asm volatile("s_waitcnt vmcnt(4)" ::: "memory");  // tile0's 8 loads landed
  __builtin_amdgcn_s_barrier();

  const int NITER = K >> 7;
  for (int i = 0; i < NITER; ++i) {
    const bool G = (i + 1 < NITER);
    const int t1 = 2 * i + 1, t2 = 2 * i + 2, t3 = 2 * i + 3;

    // r0: tile(p0) quad(mh0,nh0); stage t1's A (Al[1] free since prev r6)
    LDA_(0, 0);
    LDB_(bfrA, 0, 0);
    STG(Al, aptr, 1, 0, t1);
    STG(Al, aptr, 1, 1, t1);
    BARR();
    MMA_(bfrA, 0, 0);
    BARR();
    // r1: quad(mh0,nh1), A reused in regs
    LDB_(bfrB, 0, 1);
    BARR();
    MMA_(bfrB, 0, 1);
    BARR();
    // r2: quad(mh1,nh1), B(nh1) reused in regs
    LDA_(0, 1);
    BARR();
    MMA_(bfrB, 1, 1);
    BARR();
    // r3: quad(mh1,nh0) — all from regs; stage B(0,h0,t2) (Bl[0] free after r1);
    // vmcnt(2): drains prev-r7's B(t1) 4 + r0's A(t1) 4 before r4 reads them.
    if (G) {
      STG(Bl, bptr, 0, 0, t2);
      asm volatile("s_waitcnt vmcnt(2)" ::: "memory");
    } else {
      asm volatile("s_waitcnt vmcnt(0)" ::: "memory");
    }
    BARR();
    MMA_(bfrA, 1, 0);
    BARR();
    // r4: tile(p1) quad(mh0,nh0); stage B(0,h1,t2)
    LDA_(1, 0);
    LDB_(bfrA, 1, 0);
    if (G) STG(Bl, bptr, 0, 1, t2);
    BARR();
    MMA_(bfrA, 0, 0);
    BARR();
    // r5: quad(mh0,nh1); stage A(0,h0,t2) (Al[0] free after r2)
    LDB_(bfrB, 1, 1);
    if (G) STG(Al, aptr, 0, 0, t2);
    BARR();
    MMA_(bfrB, 0, 1);
    BARR();
    // r6: quad(mh1,nh1); stage A(0,h1,t2)
    LDA_(1, 1);
    if (G) STG(Al, aptr, 0, 1, t2);
    BARR();
    MMA_(bfrB, 1, 1);
    BARR();
    // r7: quad(mh1,nh0) — all from regs; stage B(1,both,t3) (Bl[1] free after r5);
    // vmcnt(4): drains t2's 8 loads before next r0 reads them.
    if (G) {
      STG(Bl, bptr, 1, 0, t3);
      STG(Bl, bptr, 1, 1, t3);
      asm volatile("s_waitcnt vmcnt(4)" ::: "memory");
    }
    BARR();
    MMA_(bfrA, 1, 0);
    BARR();
  }
#undef STG
#undef LDA_
#undef LDB_
#undef MMA_
#undef BARR

  // epilogue: acc[mh*4+mf][nh*2+nf]: row off = (mp>>2)*64+(mp&3)*16+g*4,
  // col off = (nfi>>1)*32 + (nfi&1)*16 + lr.
  if (EPI == 0) {
#pragma unroll
    for (int mp = 0; mp < 8; ++mp) {
      int m0 = bm + wr * 128 + (mp >> 2) * 64 + (mp & 3) * 16 + g * 4;
#pragma unroll
      for (int nfi = 0; nfi < 4; ++nfi) {
        int n = bn + wc * 64 + (nfi >> 1) * 32 + (nfi & 1) * 16 + lr;
#pragma unroll
        for (int r = 0; r < 4; ++r) C[(size_t)(m0 + r) * N + n] = acc[mp][nfi][r];
      }
    }
  } else {
    const int bi = bm >> 11;
    const int tbase = bm & 2047;
#pragma unroll
    for (int nfi = 0; nfi < 4; ++nfi) {
      int e = bn + wc * 64 + (nfi >> 1) * 32 + (nfi & 1) * 16 + lr;  // region uniform/block
      int region = e >> 11;
      int e2 = e & 2047;
      int h = e2 >> 7, d = e2 & 127;
      int bh = bi * 16 + h;
#pragma unroll
      for (int mp = 0; mp < 8; ++mp) {
        int trow = tbase + wr * 128 + (mp >> 2) * 64 + (mp & 3) * 16 + g * 4;
        if (region == 2) {
          s16x4 pk;
#pragma unroll
          for (int r = 0; r < 4; ++r) pk[r] = (short)f2bf(acc[mp][nfi][r]);
          *(s16x4*)(VT + ((size_t)bh * 128 + d) * 2048 + trow) = pk;
        } else {
          unsigned short* dst = (region == 0) ? Q : Kk;
#pragma unroll
          for (int r = 0; r < 4; ++r)
            dst[((size_t)bh * 2048 + trow + r) * 128 + d] = f2bf(acc[mp][nfi][r]);
        }
      }
    }
  }
}

// ---------------- flash attention (R8, unchanged) ----------------
__global__ __launch_bounds__(256) void flash_attn(const unsigned short* __restrict__ Qg,
                                                  const unsigned short* __restrict__ Kg,
                                                  const unsigned short* __restrict__ VTg,
                                                  unsigned short* __restrict__ Yg,
                                                  const int* __restrict__ iscausal,
                                                  const unsigned char* __restrict__ amask) {
  __shared__ __attribute__((aligned(128))) unsigned short Ks[2][64 * 128];
  __shared__ __attribute__((aligned(128))) unsigned short Vs[2][128 * 64];
  __shared__ __attribute__((aligned(128))) unsigned short Ps[4][16 * 72];

  const int t = threadIdx.x, lane = t & 63, w = t >> 6;
  const int g = lane >> 4, lr = lane & 15;
  const int id = blockIdx.x;
  const int xcd = id & 7, j5 = id >> 3;
  const int bh = xcd * 8 + (j5 >> 5);
  const int qbi = 31 - (j5 & 31);
  const int b = bh >> 4;
  const int qb = qbi * 64;
  const int causal = iscausal[0] != 0;
  const int nt = causal ? (qbi + 1) : 32;

  const unsigned short* qrow = Qg + ((size_t)bh * 2048 + qb + w * 16 + lr) * 128;
  bf16x8 qf[4];
#pragma unroll
  for (int ds = 0; ds < 4; ++ds) qf[ds] = *(const bf16x8*)(qrow + ds * 32 + g * 8);

  const unsigned short* Kbase = Kg + (size_t)bh * 2048 * 128;
  const unsigned short* Vbase = VTg + (size_t)bh * 128 * 2048;

  const int rK = t >> 4, sK = ((t & 15) ^ rK);
  const int rV = t >> 3, sV = ((t & 7) ^ ((t >> 3) & 7));

#define STAGE(KT, P)                                                                    \
  do {                                                                                  \
    const int _kv = (KT) * 64;                                                          \
    _Pragma("unroll") for (int c = 0; c < 4; ++c)                                       \
        async16(Kbase + (size_t)(_kv + c * 16 + rK) * 128 + sK * 8,                     \
                &Ks[P][c * 2048 + t * 8]);                                              \
    _Pragma("unroll") for (int c = 0; c < 4; ++c)                                       \
        async16(Vbase + (size_t)(c * 32 + rV) * 2048 + _kv + sV * 8,                    \
                &Vs[P][c * 2048 + t * 8]);                                              \
  } while (0)

  unsigned int oi[4] = {0x3F803F80u, 0x3F803F80u, 0x3F803F80u, 0x3F803F80u};
  bf16x8 ones;
  __builtin_memcpy(&ones, oi, 16);

  f32x4 acc[8] = {};
  f32x4 accl = {0.f, 0.f, 0.f, 0.f};
  float mrow[4] = {-1e30f, -1e30f, -1e30f, -1e30f};

  STAGE(0, 0);

  for (int kt = 0; kt < nt; ++kt) {
    const int p = kt & 1;
    const int kv0 = kt * 64;
    if (kt + 1 < nt) {
      STAGE(kt + 1, p ^ 1);
      BAR_VM(8);
    } else {
      BAR_VM(0);
    }

    f32x4 s[4] = {};
    __builtin_amdgcn_s_setprio(1);
#pragma unroll
    for (int cf = 0; cf < 4; ++cf)
#pragma unroll
      for (int ds = 0; ds < 4; ++ds) {
        bf16x8 kf = *(const bf16x8*)(&Ks[p][(cf * 16 + lr) * 128 + (((ds * 4 + g) ^ lr) * 8)]);
        s[cf] = __builtin_amdgcn_mfma_f32_16x16x32_bf16(qf[ds], kf, s[cf], 0, 0, 0);
      }
    __builtin_amdgcn_s_setprio(0);

    const int q0 = qb + w * 16 + g * 4;
    if (causal) {
      if (kt == qbi) {
#pragma unroll
        for (int cf = 0; cf < 4; ++cf) {
          int kvg = kv0 + cf * 16 + lr;
#pragma unroll
          for (int r = 0; r < 4; ++r)
            if (kvg > q0 + r) s[cf][r] = -1e30f;
        }
      }
    } else {
#pragma unroll
      for (int cf = 0; cf < 4; ++cf) {
        int kvg = kv0 + cf * 16 + lr;
        if (!amask[(size_t)b * 2048 + kvg]) {
#pragma unroll
          for (int r = 0; r < 4; ++r) s[cf][r] = -1e30f;
        }
      }
    }

    f32x4 lm;
#pragma unroll
    for (int r = 0; r < 4; ++r)
      lm[r] = fmaxf(fmaxf(s[0][r], s[1][r]), fmaxf(s[2][r], s[3][r]));
    bool ok = true;
#pragma unroll
    for (int r = 0; r < 4; ++r) ok = ok && (lm[r] <= mrow[r] + 8.0f);
    if (!__all(ok)) {
      f32x4 mx = lm;
#pragma unroll
      for (int off = 8; off >= 1; off >>= 1)
#pragma unroll
        for (int r = 0; r < 4; ++r) mx[r] = fmaxf(mx[r], __shfl_xor(mx[r], off));
#pragma unroll
      for (int r = 0; r < 4; ++r) {
        float mn = fmaxf(mrow[r], mx[r]);
        float corr = exp2f(mrow[r] - mn);
        mrow[r] = mn;
        accl[r] *= corr;
#pragma unroll
        for (int jf = 0; jf < 8; ++jf) acc[jf][r] *= corr;
      }
    }

#pragma unroll
    for (int cf = 0; cf < 4; ++cf)
#pragma unroll
      for (int r = 0; r < 4; ++r) s[cf][r] = exp2f(s[cf][r] - mrow[r]);

    unsigned short* Pw = &Ps[w][0];
#pragma unroll
    for (int cf = 0; cf < 4; ++cf)
#pragma unroll
      for (int r = 0; r < 4; ++r) Pw[(g * 4 + r) * 72 + cf * 16 + lr] = f2bf(s[cf][r]);
    asm volatile("s_waitcnt lgkmcnt(0)" ::: "memory");
    __builtin_amdgcn_sched_barrier(0);

    bf16x8 pa0 = *(const bf16x8*)(Pw + lr * 72 + g * 8);
    bf16x8 pa1 = *(const bf16x8*)(Pw + lr * 72 + 32 + g * 8);

    accl = __builtin_amdgcn_mfma_f32_16x16x32_bf16(pa0, ones, accl, 0, 0, 0);
    accl = __builtin_amdgcn_mfma_f32_16x16x32_bf16(pa1, ones, accl, 0, 0, 0);

    __builtin_amdgcn_s_setprio(1);
#pragma unroll
    for (int jf = 0; jf < 8; ++jf) {
      bf16x8 v0 = *(const bf16x8*)(&Vs[p][(jf * 16 + lr) * 64 + ((g ^ (lr & 7)) * 8)]);
      bf16x8 v1 = *(const bf16x8*)(&Vs[p][(jf * 16 + lr) * 64 + (((4 + g) ^ (lr & 7)) * 8)]);
      acc[jf] = __builtin_amdgcn_mfma_f32_16x16x32_bf16(pa0, v0, acc[jf], 0, 0, 0);
      acc[jf] = __builtin_amdgcn_mfma_f32_16x16x32_bf16(pa1, v1, acc[jf], 0, 0, 0);
    }
    __builtin_amdgcn_s_setprio(0);

    BAR_LGKM();
  }
#undef STAGE

  const int h = bh & 15;
  float rl[4];
#pragma unroll
  for (int r = 0; r < 4; ++r) rl[r] = __builtin_amdgcn_rcpf(accl[r]);
#pragma unroll
  for (int jf = 0; jf < 8; ++jf)
#pragma unroll
    for (int r = 0; r < 4; ++r) {
      int tt = qb + w * 16 + g * 4 + r;
      Yg[((size_t)b * 2048 + tt) * 2048 + h * 128 + jf * 16 + lr] = f2bf(acc[jf][r] * rl[r]);
    }
}

// ---------------- launch ----------------
extern "C" void kernel_launch(void* const* d_in, const int* in_sizes, int n_in, void* d_out,
                              int out_size, void* d_ws, size_t ws_size, hipStream_t stream) {
  const float* x = (const float*)d_in[0];
  const unsigned char* amask = (const unsigned char*)d_in[1];
  const int* iscausal = (const int*)d_in[2];
  const float* wqkv = (const float*)d_in[3];
  const float* wout = (const float*)d_in[4];
  float* out = (float*)d_out;

  const size_t MT = 8192, D = 2048, ND = 6144;
  unsigned short* xb = (unsigned short*)d_ws;
  unsigned short* wqkvb = xb + MT * D;
  unsigned short* woutb = wqkvb + ND * D;
  unsigned short* q = woutb + D * D;
  unsigned short* k = q + MT * D;
  unsigned short* vt = k + MT * D;
  unsigned short* y = vt + MT * D;
  float* tab = (float*)(y + MT * D);
  if (ws_size < (size_t)(100663296) * 2 + 2048 * 128 * 4) return;

  cvt_bf16<<<dim3(16384), dim3(256), 0, stream>>>(x, xb, (int)(MT * D));
  cvt_bf16<<<dim3(12288), dim3(256), 0, stream>>>(wqkv, wqkvb, (int)(ND * D));
  cvt_bf16<<<dim3(4096), dim3(256), 0, stream>>>(wout, woutb, (int)(D * D));
  rope_table<<<dim3(512), dim3(256), 0, stream>>>(tab);
  gemm256<1><<<dim3(24, 32), dim3(512), 0, stream>>>(xb, wqkvb, nullptr, 8192, 6144, 2048, q, k, vt);
  rope_apply<<<dim3(8192), dim3(256), 0, stream>>>(q, k, tab);
  flash_attn<<<dim3(2048), dim3(256), 0, stream>>>(q, k, vt, y, iscausal, amask);
  gemm256<0><<<dim3(8, 32), dim3(512), 0, stream>>>(y, woutb, out, 8192, 2048, 2048, nullptr,
                                                    nullptr, nullptr);
}